// Round 1
// baseline (549.599 us; speedup 1.0000x reference)
//
#include <hip/hip_runtime.h>

#define NN 32768   // nodes
#define BB 64      // graphs
#define MM 512     // nodes per graph
#define HH 4       // heads
#define DD 64      // head dim
#define INF 256    // input features
#define HD 256     // H*D
#define EE 524288  // edges

// ---------------------------------------------------------------------------
// GEMM: C = A @ W + bias for q/k/v (blockIdx.z selects which), fp32.
// Also accumulates global sum-of-squares of q and k into sumsq[0..1].
// ---------------------------------------------------------------------------
__global__ __launch_bounds__(256) void qkv_gemm(
    const float* __restrict__ Xq, const float* __restrict__ Xs,
    const float* __restrict__ Wq, const float* __restrict__ bq,
    const float* __restrict__ Wk, const float* __restrict__ bk,
    const float* __restrict__ Wv, const float* __restrict__ bv,
    float* __restrict__ qo, float* __restrict__ ko, float* __restrict__ vo,
    float* __restrict__ sumsq)
{
    const int which = blockIdx.z;
    const float* A    = (which == 0) ? Xq : Xs;
    const float* W    = (which == 0) ? Wq : (which == 1) ? Wk : Wv;
    const float* bias = (which == 0) ? bq : (which == 1) ? bk : bv;
    float* C          = (which == 0) ? qo : (which == 1) ? ko : vo;

    __shared__ float As[16][64 + 4];  // transposed A tile: As[k][m]
    __shared__ float Bs[16][64];      // Bs[k][n]
    __shared__ float wred[4];

    const int tid = threadIdx.x;
    const int tx = tid & 15, ty = tid >> 4;
    const int row0 = blockIdx.y * 64;
    const int col0 = blockIdx.x * 64;
    const int ar = tid >> 2, ac = (tid & 3) << 2;   // A load: 64 rows x 16 k
    const int br = tid >> 4, bc = (tid & 15) << 2;  // W load: 16 k x 64 cols

    float acc[4][4] = {};

    for (int k0 = 0; k0 < INF; k0 += 16) {
        float4 a4 = *(const float4*)&A[(size_t)(row0 + ar) * INF + k0 + ac];
        float4 w4 = *(const float4*)&W[(size_t)(k0 + br) * HD + col0 + bc];
        __syncthreads();
        As[ac + 0][ar] = a4.x;
        As[ac + 1][ar] = a4.y;
        As[ac + 2][ar] = a4.z;
        As[ac + 3][ar] = a4.w;
        *(float4*)&Bs[br][bc] = w4;
        __syncthreads();
#pragma unroll
        for (int kk = 0; kk < 16; ++kk) {
            float4 av  = *(const float4*)&As[kk][ty << 2];
            float4 bv4 = *(const float4*)&Bs[kk][tx << 2];
            float a[4] = {av.x, av.y, av.z, av.w};
            float b[4] = {bv4.x, bv4.y, bv4.z, bv4.w};
#pragma unroll
            for (int i = 0; i < 4; ++i)
#pragma unroll
                for (int j = 0; j < 4; ++j)
                    acc[i][j] = fmaf(a[i], b[j], acc[i][j]);
        }
    }

    float4 bj = *(const float4*)&bias[col0 + (tx << 2)];
    float bb[4] = {bj.x, bj.y, bj.z, bj.w};
    float loc = 0.f;
#pragma unroll
    for (int i = 0; i < 4; ++i) {
        float c0 = acc[i][0] + bb[0], c1 = acc[i][1] + bb[1];
        float c2 = acc[i][2] + bb[2], c3 = acc[i][3] + bb[3];
        *(float4*)&C[(size_t)(row0 + (ty << 2) + i) * HD + col0 + (tx << 2)] =
            make_float4(c0, c1, c2, c3);
        loc += c0 * c0 + c1 * c1 + c2 * c2 + c3 * c3;
    }

    if (which < 2) {  // q or k: global sum-of-squares for Frobenius norm
#pragma unroll
        for (int off = 32; off > 0; off >>= 1) loc += __shfl_down(loc, off, 64);
        if ((tid & 63) == 0) wred[tid >> 6] = loc;
        __syncthreads();
        if (tid == 0) atomicAdd(&sumsq[which], wred[0] + wred[1] + wred[2] + wred[3]);
    }
}

// ---------------------------------------------------------------------------
// Per (b,h): kv[64][64] = sum_m k[m]^T v[m]; k_sum, v_sum.
// kv and k_sum are pre-scaled by 1/(||q||*||k||) so downstream uses raw q.
// ---------------------------------------------------------------------------
__global__ __launch_bounds__(256) void kv_kernel(
    const float* __restrict__ k, const float* __restrict__ v,
    const float* __restrict__ sumsq,
    float* __restrict__ kv_s, float* __restrict__ ksum_s, float* __restrict__ vsum_s)
{
    const int h = blockIdx.x, b = blockIdx.y;
    __shared__ float lk[8][64], lv[8][64];
    const int tid = threadIdx.x;
    const int tx = tid & 15, ty = tid >> 4;
    float acc[4][4] = {};
    float sacc = 0.f;
    const size_t base = (size_t)b * MM * HD + (size_t)h * DD;

    for (int m0 = 0; m0 < MM; m0 += 8) {
        __syncthreads();
#pragma unroll
        for (int c = 0; c < 4; ++c) {
            int idx = tid + c * 256;            // 0..1023; uniform k/v split per c
            int i = idx & 511, mm = i >> 6, d = i & 63;
            const float* src = (idx < 512) ? k : v;
            float val = src[base + (size_t)(m0 + mm) * HD + d];
            if (idx < 512) lk[mm][d] = val; else lv[mm][d] = val;
        }
        __syncthreads();
#pragma unroll
        for (int mm = 0; mm < 8; ++mm) {
            float4 av  = *(const float4*)&lk[mm][ty << 2];
            float4 bv4 = *(const float4*)&lv[mm][tx << 2];
            float a[4] = {av.x, av.y, av.z, av.w};
            float bvals[4] = {bv4.x, bv4.y, bv4.z, bv4.w};
#pragma unroll
            for (int i = 0; i < 4; ++i)
#pragma unroll
                for (int j = 0; j < 4; ++j)
                    acc[i][j] = fmaf(a[i], bvals[j], acc[i][j]);
        }
        if (tid < 64) {
#pragma unroll
            for (int mm = 0; mm < 8; ++mm) sacc += lk[mm][tid];
        } else if (tid < 128) {
#pragma unroll
            for (int mm = 0; mm < 8; ++mm) sacc += lv[mm][tid - 64];
        }
    }

    const float inv = 1.0f / (sqrtf(sumsq[0]) * sqrtf(sumsq[1]));
    float* kvb = &kv_s[((size_t)b * HH + h) * 4096];
#pragma unroll
    for (int i = 0; i < 4; ++i) {
        *(float4*)&kvb[(size_t)((ty << 2) + i) * 64 + (tx << 2)] =
            make_float4(acc[i][0] * inv, acc[i][1] * inv, acc[i][2] * inv, acc[i][3] * inv);
    }
    if (tid < 64)        ksum_s[((size_t)b * HH + h) * 64 + tid]      = sacc * inv;
    else if (tid < 128)  vsum_s[((size_t)b * HH + h) * 64 + tid - 64] = sacc;
}

// ---------------------------------------------------------------------------
// vbar[n][d] = mean over heads of v[n][h][d]
// ---------------------------------------------------------------------------
__global__ __launch_bounds__(256) void vbar_kernel(
    const float* __restrict__ v, float* __restrict__ vbar)
{
    const int idx = blockIdx.x * 256 + threadIdx.x;   // N*64 total
    const int n = idx >> 6, d = idx & 63;
    const float* vr = &v[(size_t)n * HD + d];
    vbar[idx] = 0.25f * (vr[0] + vr[64] + vr[128] + vr[192]);
}

// ---------------------------------------------------------------------------
// deg[c] = in-degree (count over col)
// ---------------------------------------------------------------------------
__global__ __launch_bounds__(256) void deg_kernel(
    const int* __restrict__ ei, int* __restrict__ deg)
{
    const int e = blockIdx.x * 256 + threadIdx.x;
    if (e < EE) atomicAdd(&deg[ei[EE + e]], 1);
}

// ---------------------------------------------------------------------------
// attn: out[n][d] = (1/H) * sum_h (q[n,h,:]·kv_s[b,h,:,d] + vsum[b,h,d])
//                              / (q[n,h,:]·ksum_s[b,h,:] + n_nodes[b])
// One block = 64 nodes of one graph; loops over heads with LDS-staged tiles.
// ---------------------------------------------------------------------------
__global__ __launch_bounds__(256) void attn_kernel(
    const float* __restrict__ q, const float* __restrict__ kv_s,
    const float* __restrict__ ksum_s, const float* __restrict__ vsum_s,
    const int* __restrict__ n_nodes, float* __restrict__ out)
{
    const int b = blockIdx.y;
    const int m0 = blockIdx.x * 64;
    const int tid = threadIdx.x;
    const int tx = tid & 15, ty = tid >> 4;

    __shared__ float qsT[64][68];    // qsT[k][node]
    __shared__ float kvs[4096];      // kv[k][d]
    __shared__ float ksum_l[64], vsum_l[64], denom_l[64];

    float acc[4][4] = {};
    const float nn = (float)n_nodes[b];

    for (int h = 0; h < HH; ++h) {
        __syncthreads();
        {   // load q tile transposed: 64 nodes x 64 k
            const int r = tid >> 2, c0 = (tid & 3) << 4;
            const float* qrow = &q[((size_t)(b * MM + m0 + r)) * HD + h * DD];
#pragma unroll
            for (int jj = 0; jj < 4; ++jj) {
                float4 t4 = *(const float4*)&qrow[c0 + (jj << 2)];
                qsT[c0 + (jj << 2) + 0][r] = t4.x;
                qsT[c0 + (jj << 2) + 1][r] = t4.y;
                qsT[c0 + (jj << 2) + 2][r] = t4.z;
                qsT[c0 + (jj << 2) + 3][r] = t4.w;
            }
        }
        {
            const float* kvg = &kv_s[((size_t)(b * HH + h)) * 4096];
#pragma unroll
            for (int c = 0; c < 4; ++c)
                *(float4*)&kvs[c * 1024 + (tid << 2)] = *(const float4*)&kvg[c * 1024 + (tid << 2)];
        }
        if (tid < 64)       ksum_l[tid]      = ksum_s[((size_t)(b * HH + h)) * 64 + tid];
        else if (tid < 128) vsum_l[tid - 64] = vsum_s[((size_t)(b * HH + h)) * 64 + tid - 64];
        __syncthreads();

        if (tid < 64) {
            float dsum = nn;
#pragma unroll 8
            for (int kk = 0; kk < 64; ++kk) dsum += qsT[kk][tid] * ksum_l[kk];
            denom_l[tid] = dsum;
        }
        __syncthreads();

        float dot[4][4] = {};
#pragma unroll 8
        for (int kk = 0; kk < 64; ++kk) {
            float4 av  = *(const float4*)&qsT[kk][ty << 2];
            float4 bv4 = *(const float4*)&kvs[kk * 64 + (tx << 2)];
            float a[4] = {av.x, av.y, av.z, av.w};
            float bvals[4] = {bv4.x, bv4.y, bv4.z, bv4.w};
#pragma unroll
            for (int i = 0; i < 4; ++i)
#pragma unroll
                for (int j = 0; j < 4; ++j)
                    dot[i][j] = fmaf(a[i], bvals[j], dot[i][j]);
        }
        float rden[4];
#pragma unroll
        for (int i = 0; i < 4; ++i) rden[i] = 0.25f / denom_l[(ty << 2) + i];
#pragma unroll
        for (int i = 0; i < 4; ++i)
#pragma unroll
            for (int j = 0; j < 4; ++j)
                acc[i][j] += (dot[i][j] + vsum_l[(tx << 2) + j]) * rden[i];
    }

#pragma unroll
    for (int i = 0; i < 4; ++i) {
        const size_t node = (size_t)b * MM + m0 + (ty << 2) + i;
        *(float4*)&out[node * DD + (tx << 2)] =
            make_float4(acc[i][0], acc[i][1], acc[i][2], acc[i][3]);
    }
}

// ---------------------------------------------------------------------------
// GCN scatter: out[col] += (w_e / sqrt(deg[row]*deg[col])) * vbar[row]
// One wave per edge; lane = feature d.
// ---------------------------------------------------------------------------
__global__ __launch_bounds__(256) void gcn_kernel(
    const int* __restrict__ ei, const float* __restrict__ ew,
    const int* __restrict__ deg, const float* __restrict__ vbar,
    float* __restrict__ out)
{
    const int t = blockIdx.x * 256 + threadIdx.x;
    const int e = t >> 6, d = t & 63;
    const int row = ei[e], col = ei[EE + e];
    const long long prod = (long long)deg[row] * (long long)deg[col];
    float val = 0.f;
    if (prod > 0) val = ew[e] / sqrtf((float)prod);
    const float contrib = val * vbar[(size_t)row * DD + d];
    atomicAdd(&out[(size_t)col * DD + d], contrib);
}

// ---------------------------------------------------------------------------
extern "C" void kernel_launch(void* const* d_in, const int* in_sizes, int n_in,
                              void* d_out, int out_size, void* d_ws, size_t ws_size,
                              hipStream_t stream)
{
    (void)in_sizes; (void)n_in; (void)out_size; (void)ws_size;
    const float* Xq = (const float*)d_in[0];
    const float* Xs = (const float*)d_in[1];
    const float* ew = (const float*)d_in[2];
    const float* Wq = (const float*)d_in[3];
    const float* bq = (const float*)d_in[4];
    const float* Wk = (const float*)d_in[5];
    const float* bk = (const float*)d_in[6];
    const float* Wv = (const float*)d_in[7];
    const float* bv = (const float*)d_in[8];
    const int* n_nodes = (const int*)d_in[9];
    const int* ei = (const int*)d_in[10];
    float* out = (float*)d_out;
    float* ws  = (float*)d_ws;

    // workspace layout (units of 4 bytes)
    const size_t OFF_Q    = 0;
    const size_t OFF_K    = (size_t)NN * HD;        //  8388608
    const size_t OFF_V    = OFF_K * 2;              // 16777216
    const size_t OFF_SS   = OFF_K * 3;              // sumsq[2] (padded to 16)
    const size_t OFF_DEG  = OFF_SS + 16;            // NN ints
    const size_t OFF_VBAR = OFF_DEG + NN;           // NN*DD
    const size_t OFF_KV   = OFF_VBAR + (size_t)NN * DD;
    const size_t OFF_KSUM = OFF_KV + (size_t)BB * HH * DD * DD;
    const size_t OFF_VSUM = OFF_KSUM + (size_t)BB * HH * DD;
    // total ≈ 113.5 MB

    float* q      = ws + OFF_Q;
    float* k      = ws + OFF_K;
    float* v      = ws + OFF_V;
    float* sumsq  = ws + OFF_SS;
    int*   deg    = (int*)(ws + OFF_DEG);
    float* vbar   = ws + OFF_VBAR;
    float* kv_s   = ws + OFF_KV;
    float* ksum_s = ws + OFF_KSUM;
    float* vsum_s = ws + OFF_VSUM;

    // zero sumsq + deg (contiguous)
    hipMemsetAsync(sumsq, 0, (16 + NN) * sizeof(float), stream);

    deg_kernel<<<EE / 256, 256, 0, stream>>>(ei, deg);
    qkv_gemm<<<dim3(HD / 64, NN / 64, 3), 256, 0, stream>>>(
        Xq, Xs, Wq, bq, Wk, bk, Wv, bv, q, k, v, sumsq);
    kv_kernel<<<dim3(HH, BB), 256, 0, stream>>>(k, v, sumsq, kv_s, ksum_s, vsum_s);
    vbar_kernel<<<(NN * DD) / 256, 256, 0, stream>>>(v, vbar);
    attn_kernel<<<dim3(MM / 64, BB), 256, 0, stream>>>(
        q, kv_s, ksum_s, vsum_s, n_nodes, out);
    gcn_kernel<<<EE / 4, 256, 0, stream>>>(ei, ew, deg, vbar, out);
}

// Round 2
// 467.686 us; speedup vs baseline: 1.1751x; 1.1751x over previous
//
#include <hip/hip_runtime.h>

#define NN 32768   // nodes
#define BB 64      // graphs
#define MM 512     // nodes per graph
#define HH 4       // heads
#define DD 64      // head dim
#define INF 256    // input features
#define HD 256     // H*D
#define EE 524288  // edges

typedef unsigned short ushort;
typedef unsigned int uint;
typedef short s16x8 __attribute__((ext_vector_type(8)));
typedef ushort u16x8 __attribute__((ext_vector_type(8)));
typedef float f32x4 __attribute__((ext_vector_type(4)));

__device__ __forceinline__ ushort f2bf(float f) {
    uint u = __float_as_uint(f);
    return (ushort)((u + 0x7fffu + ((u >> 16) & 1u)) >> 16);
}

// ---------------------------------------------------------------------------
// Convert 3 weight matrices [K=256][N=256] fp32 -> transposed bf16 [N][K].
// ---------------------------------------------------------------------------
__global__ __launch_bounds__(256) void convert_w(
    const float* __restrict__ Wq, const float* __restrict__ Wk,
    const float* __restrict__ Wv, ushort* __restrict__ WT)
{
    const int id = blockIdx.x * 256 + threadIdx.x;   // 3*65536 total
    const int mat = id >> 16, rem = id & 65535;
    const int n = rem >> 8, kk = rem & 255;
    const float* W = (mat == 0) ? Wq : (mat == 1) ? Wk : Wv;
    WT[id] = f2bf(W[kk * 256 + n]);  // WT[mat][n][kk]
}

// ---------------------------------------------------------------------------
// bf16 MFMA GEMM: C = A @ W + bias  (z selects q/k/v). A fp32 in global,
// cast to bf16 while staging to LDS. Accumulate fp32 via MFMA. Also
// accumulates global sum(C^2) for q and k into sumsq[0..1].
// Tile 128x128, BK=32, 4 waves each computing 64x64 via 4x4 16x16x32 tiles.
// ---------------------------------------------------------------------------
#define BKP 40   // LDS row pitch in bf16 elems (80 B: 16B-aligned, conflict-lite)
__global__ __launch_bounds__(256) void qkv_gemm(
    const float* __restrict__ Xq, const float* __restrict__ Xs,
    const ushort* __restrict__ WT,
    const float* __restrict__ bq, const float* __restrict__ bk,
    const float* __restrict__ bv,
    float* __restrict__ qo, float* __restrict__ ko, float* __restrict__ vo,
    float* __restrict__ sumsq)
{
    const int which = blockIdx.z;
    const float* A    = (which == 0) ? Xq : Xs;
    const ushort* W   = WT + (size_t)which * 65536;
    const float* bias = (which == 0) ? bq : (which == 1) ? bk : bv;
    float* C          = (which == 0) ? qo : (which == 1) ? ko : vo;

    __shared__ ushort Asu[128 * BKP];
    __shared__ ushort Bsu[128 * BKP];
    __shared__ float wred[4];

    const int t = threadIdx.x;
    const int l = t & 63, w = t >> 6;
    const int row0 = blockIdx.y * 128;
    const int col0 = blockIdx.x * 128;
    const int wr = (w & 1) * 64, wc = (w >> 1) * 64;
    const int sr = t >> 1, sh = (t & 1) * 16;   // staging: row, k-half

    f32x4 acc[4][4] = {};

    for (int k0 = 0; k0 < INF; k0 += 32) {
        // global loads (before barrier, to overlap)
        const float* ap = &A[(size_t)(row0 + sr) * INF + k0 + sh];
        float4 a0 = *(const float4*)(ap + 0);
        float4 a1 = *(const float4*)(ap + 4);
        float4 a2 = *(const float4*)(ap + 8);
        float4 a3 = *(const float4*)(ap + 12);
        const ushort* bp = &W[(size_t)(col0 + sr) * INF + k0 + sh];
        u16x8 b0 = *(const u16x8*)(bp + 0);
        u16x8 b1 = *(const u16x8*)(bp + 8);

        __syncthreads();
        u16x8 pa0, pa1;
        pa0[0] = f2bf(a0.x); pa0[1] = f2bf(a0.y); pa0[2] = f2bf(a0.z); pa0[3] = f2bf(a0.w);
        pa0[4] = f2bf(a1.x); pa0[5] = f2bf(a1.y); pa0[6] = f2bf(a1.z); pa0[7] = f2bf(a1.w);
        pa1[0] = f2bf(a2.x); pa1[1] = f2bf(a2.y); pa1[2] = f2bf(a2.z); pa1[3] = f2bf(a2.w);
        pa1[4] = f2bf(a3.x); pa1[5] = f2bf(a3.y); pa1[6] = f2bf(a3.z); pa1[7] = f2bf(a3.w);
        *(u16x8*)&Asu[sr * BKP + sh] = pa0;
        *(u16x8*)&Asu[sr * BKP + sh + 8] = pa1;
        *(u16x8*)&Bsu[sr * BKP + sh] = b0;
        *(u16x8*)&Bsu[sr * BKP + sh + 8] = b1;
        __syncthreads();

        const int fr = l & 15, kg = (l >> 4) * 8;
        s16x8 af[4], bf[4];
#pragma unroll
        for (int i = 0; i < 4; ++i)
            af[i] = *(const s16x8*)&Asu[(wr + i * 16 + fr) * BKP + kg];
#pragma unroll
        for (int j = 0; j < 4; ++j)
            bf[j] = *(const s16x8*)&Bsu[(wc + j * 16 + fr) * BKP + kg];
#pragma unroll
        for (int i = 0; i < 4; ++i)
#pragma unroll
            for (int j = 0; j < 4; ++j)
                acc[i][j] = __builtin_amdgcn_mfma_f32_16x16x32_bf16(
                    af[i], bf[j], acc[i][j], 0, 0, 0);
    }

    // epilogue: bias, store, sum-of-squares
    float loc = 0.f;
#pragma unroll
    for (int j = 0; j < 4; ++j) {
        const int colg = col0 + wc + j * 16 + (l & 15);
        const float bj = bias[colg];
#pragma unroll
        for (int i = 0; i < 4; ++i) {
            const int rowg = row0 + wr + i * 16 + (l >> 4) * 4;
#pragma unroll
            for (int m = 0; m < 4; ++m) {
                float cv = acc[i][j][m] + bj;
                C[(size_t)(rowg + m) * HD + colg] = cv;
                loc += cv * cv;
            }
        }
    }
    if (which < 2) {
#pragma unroll
        for (int off = 32; off > 0; off >>= 1) loc += __shfl_down(loc, off, 64);
        if (l == 0) wred[w] = loc;
        __syncthreads();
        if (t == 0) atomicAdd(&sumsq[which], wred[0] + wred[1] + wred[2] + wred[3]);
    }
}

// ---------------------------------------------------------------------------
// Per (b,h,split): partial kv[64][64] = sum_m k^T v over 64 rows; partial
// k_sum, v_sum. Raw (unscaled) accumulation via atomicAdd; attn applies
// the 1/(||q||*||k||) scale.
// ---------------------------------------------------------------------------
__global__ __launch_bounds__(256) void kv_kernel(
    const float* __restrict__ k, const float* __restrict__ v,
    float* __restrict__ kv_s, float* __restrict__ ksum_s, float* __restrict__ vsum_s)
{
    const int h = blockIdx.x, b = blockIdx.y;
    const int m_base = blockIdx.z * 64;
    __shared__ float lk[8][64], lv[8][64];
    const int tid = threadIdx.x;
    const int tx = tid & 15, ty = tid >> 4;
    float acc[4][4] = {};
    float sacc = 0.f;
    const size_t base = (size_t)b * MM * HD + (size_t)h * DD;

    const int half = tid >> 7;          // 0: k, 1: v
    const int li = tid & 127;           // float4 index within half
    const int lmm = li >> 4, ld = (li & 15) << 2;
    const float* src = half ? v : k;

    for (int m0 = m_base; m0 < m_base + 64; m0 += 8) {
        __syncthreads();
        float4 val = *(const float4*)&src[base + (size_t)(m0 + lmm) * HD + ld];
        if (half) *(float4*)&lv[lmm][ld] = val;
        else      *(float4*)&lk[lmm][ld] = val;
        __syncthreads();
#pragma unroll
        for (int mm = 0; mm < 8; ++mm) {
            float4 av  = *(const float4*)&lk[mm][ty << 2];
            float4 bv4 = *(const float4*)&lv[mm][tx << 2];
            float a[4] = {av.x, av.y, av.z, av.w};
            float bvals[4] = {bv4.x, bv4.y, bv4.z, bv4.w};
#pragma unroll
            for (int i = 0; i < 4; ++i)
#pragma unroll
                for (int j = 0; j < 4; ++j)
                    acc[i][j] = fmaf(a[i], bvals[j], acc[i][j]);
        }
        if (tid < 64) {
#pragma unroll
            for (int mm = 0; mm < 8; ++mm) sacc += lk[mm][tid];
        } else if (tid < 128) {
#pragma unroll
            for (int mm = 0; mm < 8; ++mm) sacc += lv[mm][tid - 64];
        }
    }

    float* kvb = &kv_s[((size_t)b * HH + h) * 4096];
#pragma unroll
    for (int i = 0; i < 4; ++i)
#pragma unroll
        for (int j = 0; j < 4; ++j)
            atomicAdd(&kvb[(size_t)((ty << 2) + i) * 64 + (tx << 2) + j], acc[i][j]);
    if (tid < 64)        atomicAdd(&ksum_s[((size_t)b * HH + h) * 64 + tid], sacc);
    else if (tid < 128)  atomicAdd(&vsum_s[((size_t)b * HH + h) * 64 + tid - 64], sacc);
}

// ---------------------------------------------------------------------------
__global__ __launch_bounds__(256) void vbar_kernel(
    const float* __restrict__ v, float* __restrict__ vbar)
{
    const int idx = blockIdx.x * 256 + threadIdx.x;   // N*64 total
    const int n = idx >> 6, d = idx & 63;
    const float* vr = &v[(size_t)n * HD + d];
    vbar[idx] = 0.25f * (vr[0] + vr[64] + vr[128] + vr[192]);
}

// ---------------------------------------------------------------------------
__global__ __launch_bounds__(256) void deg_kernel(
    const int* __restrict__ ei, int* __restrict__ deg)
{
    const int e = blockIdx.x * 256 + threadIdx.x;
    if (e < EE) atomicAdd(&deg[ei[EE + e]], 1);
}

// ---------------------------------------------------------------------------
// attn: out[n][d] = (1/H) * sum_h (inv*q·KV + vsum) / (inv*q·KS + n_nodes)
// ---------------------------------------------------------------------------
__global__ __launch_bounds__(256) void attn_kernel(
    const float* __restrict__ q, const float* __restrict__ kv_s,
    const float* __restrict__ ksum_s, const float* __restrict__ vsum_s,
    const float* __restrict__ sumsq,
    const int* __restrict__ n_nodes, float* __restrict__ out)
{
    const int b = blockIdx.y;
    const int m0 = blockIdx.x * 64;
    const int tid = threadIdx.x;
    const int tx = tid & 15, ty = tid >> 4;

    __shared__ float qsT[64][68];    // qsT[k][node]
    __shared__ float kvs[4096];      // kv[k][d]
    __shared__ float ksum_l[64], vsum_l[64], denom_l[64];

    float acc[4][4] = {};
    const float nn = (float)n_nodes[b];
    const float inv = 1.0f / (sqrtf(sumsq[0]) * sqrtf(sumsq[1]));

    for (int h = 0; h < HH; ++h) {
        __syncthreads();
        {   // load q tile transposed: 64 nodes x 64 k
            const int r = tid >> 2, c0 = (tid & 3) << 4;
            const float* qrow = &q[((size_t)(b * MM + m0 + r)) * HD + h * DD];
#pragma unroll
            for (int jj = 0; jj < 4; ++jj) {
                float4 t4 = *(const float4*)&qrow[c0 + (jj << 2)];
                qsT[c0 + (jj << 2) + 0][r] = t4.x;
                qsT[c0 + (jj << 2) + 1][r] = t4.y;
                qsT[c0 + (jj << 2) + 2][r] = t4.z;
                qsT[c0 + (jj << 2) + 3][r] = t4.w;
            }
        }
        {
            const float* kvg = &kv_s[((size_t)(b * HH + h)) * 4096];
#pragma unroll
            for (int c = 0; c < 4; ++c)
                *(float4*)&kvs[c * 1024 + (tid << 2)] = *(const float4*)&kvg[c * 1024 + (tid << 2)];
        }
        if (tid < 64)       ksum_l[tid]      = ksum_s[((size_t)(b * HH + h)) * 64 + tid];
        else if (tid < 128) vsum_l[tid - 64] = vsum_s[((size_t)(b * HH + h)) * 64 + tid - 64];
        __syncthreads();

        if (tid < 64) {
            float dsum = 0.f;
#pragma unroll 8
            for (int kk = 0; kk < 64; ++kk) dsum += qsT[kk][tid] * ksum_l[kk];
            denom_l[tid] = nn + inv * dsum;
        }
        __syncthreads();

        float dot[4][4] = {};
#pragma unroll 8
        for (int kk = 0; kk < 64; ++kk) {
            float4 av  = *(const float4*)&qsT[kk][ty << 2];
            float4 bv4 = *(const float4*)&kvs[kk * 64 + (tx << 2)];
            float a[4] = {av.x, av.y, av.z, av.w};
            float bvals[4] = {bv4.x, bv4.y, bv4.z, bv4.w};
#pragma unroll
            for (int i = 0; i < 4; ++i)
#pragma unroll
                for (int j = 0; j < 4; ++j)
                    dot[i][j] = fmaf(a[i], bvals[j], dot[i][j]);
        }
        float rden[4];
#pragma unroll
        for (int i = 0; i < 4; ++i) rden[i] = 0.25f / denom_l[(ty << 2) + i];
#pragma unroll
        for (int i = 0; i < 4; ++i)
#pragma unroll
            for (int j = 0; j < 4; ++j)
                acc[i][j] += (inv * dot[i][j] + vsum_l[(tx << 2) + j]) * rden[i];
    }

#pragma unroll
    for (int i = 0; i < 4; ++i) {
        const size_t node = (size_t)b * MM + m0 + (ty << 2) + i;
        *(float4*)&out[node * DD + (tx << 2)] =
            make_float4(acc[i][0], acc[i][1], acc[i][2], acc[i][3]);
    }
}

// ---------------------------------------------------------------------------
// GCN scatter: out[col] += (w_e / sqrt(deg[row]*deg[col])) * vbar[row]
// ---------------------------------------------------------------------------
__global__ __launch_bounds__(256) void gcn_kernel(
    const int* __restrict__ ei, const float* __restrict__ ew,
    const int* __restrict__ deg, const float* __restrict__ vbar,
    float* __restrict__ out)
{
    const int t = blockIdx.x * 256 + threadIdx.x;
    const int e = t >> 6, d = t & 63;
    const int row = ei[e], col = ei[EE + e];
    const long long prod = (long long)deg[row] * (long long)deg[col];
    float val = 0.f;
    if (prod > 0) val = ew[e] / sqrtf((float)prod);
    const float contrib = val * vbar[(size_t)row * DD + d];
    atomicAdd(&out[(size_t)col * DD + d], contrib);
}

// ---------------------------------------------------------------------------
extern "C" void kernel_launch(void* const* d_in, const int* in_sizes, int n_in,
                              void* d_out, int out_size, void* d_ws, size_t ws_size,
                              hipStream_t stream)
{
    (void)in_sizes; (void)n_in; (void)out_size; (void)ws_size;
    const float* Xq = (const float*)d_in[0];
    const float* Xs = (const float*)d_in[1];
    const float* ew = (const float*)d_in[2];
    const float* Wq = (const float*)d_in[3];
    const float* bq = (const float*)d_in[4];
    const float* Wk = (const float*)d_in[5];
    const float* bk = (const float*)d_in[6];
    const float* Wv = (const float*)d_in[7];
    const float* bv = (const float*)d_in[8];
    const int* n_nodes = (const int*)d_in[9];
    const int* ei = (const int*)d_in[10];
    float* out = (float*)d_out;
    float* ws  = (float*)d_ws;

    // workspace layout (float units). The alias region is used for WT (bf16
    // weights, live only through qkv_gemm) then reused for deg/kv/sums/vbar.
    const size_t OFF_Q     = 0;
    const size_t OFF_K     = (size_t)NN * HD;          //  8388608
    const size_t OFF_V     = OFF_K * 2;                // 16777216
    const size_t OFF_SS    = OFF_K * 3;                // 25165824, 16 floats
    const size_t OFF_ALIAS = OFF_SS + 16;
    const size_t OFF_DEG   = OFF_ALIAS;                // NN ints
    const size_t OFF_KV    = OFF_DEG + NN;             // BB*HH*4096
    const size_t OFF_KSUM  = OFF_KV + (size_t)BB * HH * DD * DD;
    const size_t OFF_VSUM  = OFF_KSUM + (size_t)BB * HH * DD;
    const size_t OFF_VBAR  = OFF_VSUM + (size_t)BB * HH * DD;
    // total = OFF_VBAR + NN*DD ~= 113.5 MB (same footprint as round 1)

    float* q      = ws + OFF_Q;
    float* k      = ws + OFF_K;
    float* v      = ws + OFF_V;
    float* sumsq  = ws + OFF_SS;
    ushort* WT    = (ushort*)(ws + OFF_ALIAS);         // overlaps deg/kv: dead after gemm
    int*   deg    = (int*)(ws + OFF_DEG);
    float* kv_s   = ws + OFF_KV;
    float* ksum_s = ws + OFF_KSUM;
    float* vsum_s = ws + OFF_VSUM;
    float* vbar   = ws + OFF_VBAR;

    hipMemsetAsync(sumsq, 0, 16 * sizeof(float), stream);
    convert_w<<<768, 256, 0, stream>>>(Wq, Wk, Wv, WT);
    qkv_gemm<<<dim3(2, 256, 3), 256, 0, stream>>>(
        Xq, Xs, WT, bq, bk, bv, q, k, v, sumsq);
    // WT dead from here; zero deg + kv + ksum + vsum (contiguous)
    hipMemsetAsync(ws + OFF_ALIAS, 0,
                   (NN + (size_t)BB * HH * DD * DD + 2 * (size_t)BB * HH * DD) * sizeof(float),
                   stream);
    deg_kernel<<<EE / 256, 256, 0, stream>>>(ei, deg);
    kv_kernel<<<dim3(HH, BB, 8), 256, 0, stream>>>(k, v, kv_s, ksum_s, vsum_s);
    vbar_kernel<<<(NN * DD) / 256, 256, 0, stream>>>(v, vbar);
    attn_kernel<<<dim3(MM / 64, BB), 256, 0, stream>>>(
        q, kv_s, ksum_s, vsum_s, sumsq, n_nodes, out);
    gcn_kernel<<<EE / 4, 256, 0, stream>>>(ei, ew, deg, vbar, out);
}

// Round 3
// 398.754 us; speedup vs baseline: 1.3783x; 1.1729x over previous
//
#include <hip/hip_runtime.h>

#define NN 32768   // nodes
#define BB 64      // graphs
#define MM 512     // nodes per graph
#define HH 4       // heads
#define DD 64      // head dim
#define INF 256    // input features
#define HD 256     // H*D
#define EE 524288  // edges

typedef unsigned short ushort;
typedef unsigned int uint;
typedef short s16x8 __attribute__((ext_vector_type(8)));
typedef ushort u16x8 __attribute__((ext_vector_type(8)));
typedef float f32x4 __attribute__((ext_vector_type(4)));

__device__ __forceinline__ ushort f2bf(float f) {
    uint u = __float_as_uint(f);
    return (ushort)((u + 0x7fffu + ((u >> 16) & 1u)) >> 16);
}

// ---------------------------------------------------------------------------
// Convert 3 weight matrices [K=256][N=256] fp32 -> transposed bf16 [N][K].
// ---------------------------------------------------------------------------
__global__ __launch_bounds__(256) void convert_w(
    const float* __restrict__ Wq, const float* __restrict__ Wk,
    const float* __restrict__ Wv, ushort* __restrict__ WT)
{
    const int id = blockIdx.x * 256 + threadIdx.x;   // 3*65536 total
    const int mat = id >> 16, rem = id & 65535;
    const int n = rem >> 8, kk = rem & 255;
    const float* W = (mat == 0) ? Wq : (mat == 1) ? Wk : Wv;
    WT[id] = f2bf(W[kk * 256 + n]);  // WT[mat][n][kk]
}

// ---------------------------------------------------------------------------
// bf16 MFMA GEMM: C = A @ W + bias  (z selects q/k/v). Tile 128x128, BK=32.
// ---------------------------------------------------------------------------
#define BKP 40
__global__ __launch_bounds__(256) void qkv_gemm(
    const float* __restrict__ Xq, const float* __restrict__ Xs,
    const ushort* __restrict__ WT,
    const float* __restrict__ bq, const float* __restrict__ bk,
    const float* __restrict__ bv,
    float* __restrict__ qo, float* __restrict__ ko, float* __restrict__ vo,
    float* __restrict__ sumsq)
{
    const int which = blockIdx.z;
    const float* A    = (which == 0) ? Xq : Xs;
    const ushort* W   = WT + (size_t)which * 65536;
    const float* bias = (which == 0) ? bq : (which == 1) ? bk : bv;
    float* C          = (which == 0) ? qo : (which == 1) ? ko : vo;

    __shared__ ushort Asu[128 * BKP];
    __shared__ ushort Bsu[128 * BKP];
    __shared__ float wred[4];

    const int t = threadIdx.x;
    const int l = t & 63, w = t >> 6;
    const int row0 = blockIdx.y * 128;
    const int col0 = blockIdx.x * 128;
    const int wr = (w & 1) * 64, wc = (w >> 1) * 64;
    const int sr = t >> 1, sh = (t & 1) * 16;

    f32x4 acc[4][4] = {};

    for (int k0 = 0; k0 < INF; k0 += 32) {
        const float* ap = &A[(size_t)(row0 + sr) * INF + k0 + sh];
        float4 a0 = *(const float4*)(ap + 0);
        float4 a1 = *(const float4*)(ap + 4);
        float4 a2 = *(const float4*)(ap + 8);
        float4 a3 = *(const float4*)(ap + 12);
        const ushort* bp = &W[(size_t)(col0 + sr) * INF + k0 + sh];
        u16x8 b0 = *(const u16x8*)(bp + 0);
        u16x8 b1 = *(const u16x8*)(bp + 8);

        __syncthreads();
        u16x8 pa0, pa1;
        pa0[0] = f2bf(a0.x); pa0[1] = f2bf(a0.y); pa0[2] = f2bf(a0.z); pa0[3] = f2bf(a0.w);
        pa0[4] = f2bf(a1.x); pa0[5] = f2bf(a1.y); pa0[6] = f2bf(a1.z); pa0[7] = f2bf(a1.w);
        pa1[0] = f2bf(a2.x); pa1[1] = f2bf(a2.y); pa1[2] = f2bf(a2.z); pa1[3] = f2bf(a2.w);
        pa1[4] = f2bf(a3.x); pa1[5] = f2bf(a3.y); pa1[6] = f2bf(a3.z); pa1[7] = f2bf(a3.w);
        *(u16x8*)&Asu[sr * BKP + sh] = pa0;
        *(u16x8*)&Asu[sr * BKP + sh + 8] = pa1;
        *(u16x8*)&Bsu[sr * BKP + sh] = b0;
        *(u16x8*)&Bsu[sr * BKP + sh + 8] = b1;
        __syncthreads();

        const int fr = l & 15, kg = (l >> 4) * 8;
        s16x8 af[4], bf[4];
#pragma unroll
        for (int i = 0; i < 4; ++i)
            af[i] = *(const s16x8*)&Asu[(wr + i * 16 + fr) * BKP + kg];
#pragma unroll
        for (int j = 0; j < 4; ++j)
            bf[j] = *(const s16x8*)&Bsu[(wc + j * 16 + fr) * BKP + kg];
#pragma unroll
        for (int i = 0; i < 4; ++i)
#pragma unroll
            for (int j = 0; j < 4; ++j)
                acc[i][j] = __builtin_amdgcn_mfma_f32_16x16x32_bf16(
                    af[i], bf[j], acc[i][j], 0, 0, 0);
    }

    float loc = 0.f;
#pragma unroll
    for (int j = 0; j < 4; ++j) {
        const int colg = col0 + wc + j * 16 + (l & 15);
        const float bj = bias[colg];
#pragma unroll
        for (int i = 0; i < 4; ++i) {
            const int rowg = row0 + wr + i * 16 + (l >> 4) * 4;
#pragma unroll
            for (int m = 0; m < 4; ++m) {
                float cv = acc[i][j][m] + bj;
                C[(size_t)(rowg + m) * HD + colg] = cv;
                loc += cv * cv;
            }
        }
    }
    if (which < 2) {
#pragma unroll
        for (int off = 32; off > 0; off >>= 1) loc += __shfl_down(loc, off, 64);
        if (l == 0) wred[w] = loc;
        __syncthreads();
        if (t == 0) atomicAdd(&sumsq[which], wred[0] + wred[1] + wred[2] + wred[3]);
    }
}

// ---------------------------------------------------------------------------
// Per (b,h,split): partial kv = k^T v over 64 rows; partial k_sum, v_sum.
// ---------------------------------------------------------------------------
__global__ __launch_bounds__(256) void kv_kernel(
    const float* __restrict__ k, const float* __restrict__ v,
    float* __restrict__ kv_s, float* __restrict__ ksum_s, float* __restrict__ vsum_s)
{
    const int h = blockIdx.x, b = blockIdx.y;
    const int m_base = blockIdx.z * 64;
    __shared__ float lk[8][64], lv[8][64];
    const int tid = threadIdx.x;
    const int tx = tid & 15, ty = tid >> 4;
    float acc[4][4] = {};
    float sacc = 0.f;
    const size_t base = (size_t)b * MM * HD + (size_t)h * DD;

    const int half = tid >> 7;
    const int li = tid & 127;
    const int lmm = li >> 4, ld = (li & 15) << 2;
    const float* src = half ? v : k;

    for (int m0 = m_base; m0 < m_base + 64; m0 += 8) {
        __syncthreads();
        float4 val = *(const float4*)&src[base + (size_t)(m0 + lmm) * HD + ld];
        if (half) *(float4*)&lv[lmm][ld] = val;
        else      *(float4*)&lk[lmm][ld] = val;
        __syncthreads();
#pragma unroll
        for (int mm = 0; mm < 8; ++mm) {
            float4 av  = *(const float4*)&lk[mm][ty << 2];
            float4 bv4 = *(const float4*)&lv[mm][tx << 2];
            float a[4] = {av.x, av.y, av.z, av.w};
            float bvals[4] = {bv4.x, bv4.y, bv4.z, bv4.w};
#pragma unroll
            for (int i = 0; i < 4; ++i)
#pragma unroll
                for (int j = 0; j < 4; ++j)
                    acc[i][j] = fmaf(a[i], bvals[j], acc[i][j]);
        }
        if (tid < 64) {
#pragma unroll
            for (int mm = 0; mm < 8; ++mm) sacc += lk[mm][tid];
        } else if (tid < 128) {
#pragma unroll
            for (int mm = 0; mm < 8; ++mm) sacc += lv[mm][tid - 64];
        }
    }

    float* kvb = &kv_s[((size_t)b * HH + h) * 4096];
#pragma unroll
    for (int i = 0; i < 4; ++i)
#pragma unroll
        for (int j = 0; j < 4; ++j)
            atomicAdd(&kvb[(size_t)((ty << 2) + i) * 64 + (tx << 2) + j], acc[i][j]);
    if (tid < 64)        atomicAdd(&ksum_s[((size_t)b * HH + h) * 64 + tid], sacc);
    else if (tid < 128)  atomicAdd(&vsum_s[((size_t)b * HH + h) * 64 + tid - 64], sacc);
}

// ---------------------------------------------------------------------------
__global__ __launch_bounds__(256) void vbar_kernel(
    const float* __restrict__ v, float* __restrict__ vbar)
{
    const int idx = blockIdx.x * 256 + threadIdx.x;
    const int n = idx >> 6, d = idx & 63;
    const float* vr = &v[(size_t)n * HD + d];
    vbar[idx] = 0.25f * (vr[0] + vr[64] + vr[128] + vr[192]);
}

// ---------------------------------------------------------------------------
__global__ __launch_bounds__(256) void deg_kernel(
    const int* __restrict__ ei, int* __restrict__ deg)
{
    const int e = blockIdx.x * 256 + threadIdx.x;
    if (e < EE) atomicAdd(&deg[ei[EE + e]], 1);
}

// ---------------------------------------------------------------------------
// Exclusive prefix sum of deg[NN] -> offsets[NN+1]. One block, 1024 threads,
// 32 elements per thread.
// ---------------------------------------------------------------------------
__global__ __launch_bounds__(1024) void scan_kernel(
    const int* __restrict__ deg, int* __restrict__ offsets)
{
    __shared__ int part[1024];
    const int tid = threadIdx.x;
    const int base = tid * 32;
    int loc[32];
    int s = 0;
#pragma unroll
    for (int i = 0; i < 32; ++i) { loc[i] = s; s += deg[base + i]; }
    part[tid] = s;
    __syncthreads();
    for (int off = 1; off < 1024; off <<= 1) {
        int a = part[tid];
        int b2 = (tid >= off) ? part[tid - off] : 0;
        __syncthreads();
        part[tid] = a + b2;
        __syncthreads();
    }
    const int prev = (tid == 0) ? 0 : part[tid - 1];
#pragma unroll
    for (int i = 0; i < 32; ++i) offsets[base + i] = prev + loc[i];
    if (tid == 1023) offsets[NN] = prev + s;
}

// ---------------------------------------------------------------------------
// Scatter edges into destination buckets: rowbuf/valbuf grouped by col.
// ---------------------------------------------------------------------------
__global__ __launch_bounds__(256) void bucket_kernel(
    const int* __restrict__ ei, const float* __restrict__ ew,
    const int* __restrict__ deg, const int* __restrict__ offsets,
    int* __restrict__ cursor, int* __restrict__ rowbuf, float* __restrict__ valbuf)
{
    const int e = blockIdx.x * 256 + threadIdx.x;
    if (e >= EE) return;
    const int row = ei[e], col = ei[EE + e];
    const long long prod = (long long)deg[row] * (long long)deg[col];
    float val = 0.f;
    if (prod > 0) val = ew[e] * __frsqrt_rn((float)prod);
    const int pos = atomicAdd(&cursor[col], 1);
    const int idx = offsets[col] + pos;
    rowbuf[idx] = row;
    valbuf[idx] = val;
}

// ---------------------------------------------------------------------------
// attn: out[n][d] = (1/H) * sum_h (inv*q·KV + vsum) / (inv*q·KS + n_nodes)
// ---------------------------------------------------------------------------
__global__ __launch_bounds__(256) void attn_kernel(
    const float* __restrict__ q, const float* __restrict__ kv_s,
    const float* __restrict__ ksum_s, const float* __restrict__ vsum_s,
    const float* __restrict__ sumsq,
    const int* __restrict__ n_nodes, float* __restrict__ out)
{
    const int b = blockIdx.y;
    const int m0 = blockIdx.x * 64;
    const int tid = threadIdx.x;
    const int tx = tid & 15, ty = tid >> 4;

    __shared__ float qsT[64][68];
    __shared__ float kvs[4096];
    __shared__ float ksum_l[64], vsum_l[64], denom_l[64];

    float acc[4][4] = {};
    const float nn = (float)n_nodes[b];
    const float inv = 1.0f / (sqrtf(sumsq[0]) * sqrtf(sumsq[1]));

    for (int h = 0; h < HH; ++h) {
        __syncthreads();
        {
            const int r = tid >> 2, c0 = (tid & 3) << 4;
            const float* qrow = &q[((size_t)(b * MM + m0 + r)) * HD + h * DD];
#pragma unroll
            for (int jj = 0; jj < 4; ++jj) {
                float4 t4 = *(const float4*)&qrow[c0 + (jj << 2)];
                qsT[c0 + (jj << 2) + 0][r] = t4.x;
                qsT[c0 + (jj << 2) + 1][r] = t4.y;
                qsT[c0 + (jj << 2) + 2][r] = t4.z;
                qsT[c0 + (jj << 2) + 3][r] = t4.w;
            }
        }
        {
            const float* kvg = &kv_s[((size_t)(b * HH + h)) * 4096];
#pragma unroll
            for (int c = 0; c < 4; ++c)
                *(float4*)&kvs[c * 1024 + (tid << 2)] = *(const float4*)&kvg[c * 1024 + (tid << 2)];
        }
        if (tid < 64)       ksum_l[tid]      = ksum_s[((size_t)(b * HH + h)) * 64 + tid];
        else if (tid < 128) vsum_l[tid - 64] = vsum_s[((size_t)(b * HH + h)) * 64 + tid - 64];
        __syncthreads();

        if (tid < 64) {
            float dsum = 0.f;
#pragma unroll 8
            for (int kk = 0; kk < 64; ++kk) dsum += qsT[kk][tid] * ksum_l[kk];
            denom_l[tid] = nn + inv * dsum;
        }
        __syncthreads();

        float dot[4][4] = {};
#pragma unroll 8
        for (int kk = 0; kk < 64; ++kk) {
            float4 av  = *(const float4*)&qsT[kk][ty << 2];
            float4 bv4 = *(const float4*)&kvs[kk * 64 + (tx << 2)];
            float a[4] = {av.x, av.y, av.z, av.w};
            float bvals[4] = {bv4.x, bv4.y, bv4.z, bv4.w};
#pragma unroll
            for (int i = 0; i < 4; ++i)
#pragma unroll
                for (int j = 0; j < 4; ++j)
                    dot[i][j] = fmaf(a[i], bvals[j], dot[i][j]);
        }
        float rden[4];
#pragma unroll
        for (int i = 0; i < 4; ++i) rden[i] = 0.25f / denom_l[(ty << 2) + i];
#pragma unroll
        for (int i = 0; i < 4; ++i)
#pragma unroll
            for (int j = 0; j < 4; ++j)
                acc[i][j] += (inv * dot[i][j] + vsum_l[(tx << 2) + j]) * rden[i];
    }

#pragma unroll
    for (int i = 0; i < 4; ++i) {
        const size_t node = (size_t)b * MM + m0 + (ty << 2) + i;
        *(float4*)&out[node * DD + (tx << 2)] =
            make_float4(acc[i][0], acc[i][1], acc[i][2], acc[i][3]);
    }
}

// ---------------------------------------------------------------------------
// GCN gather: one wave per destination node; lane = feature.
// out[n] += sum over incoming edges of val * vbar[row]. No atomics.
// ---------------------------------------------------------------------------
__global__ __launch_bounds__(256) void gcn_gather(
    const int* __restrict__ offsets, const int* __restrict__ rowbuf,
    const float* __restrict__ valbuf, const float* __restrict__ vbar,
    float* __restrict__ out)
{
    const int t = blockIdx.x * 256 + threadIdx.x;
    const int n = t >> 6, d = t & 63;
    const int s = offsets[n], e = offsets[n + 1];
    float acc = 0.f;
    int i = s;
    for (; i + 4 <= e; i += 4) {
        const int r0 = rowbuf[i], r1 = rowbuf[i + 1], r2 = rowbuf[i + 2], r3 = rowbuf[i + 3];
        const float w0 = valbuf[i], w1 = valbuf[i + 1], w2 = valbuf[i + 2], w3 = valbuf[i + 3];
        acc += w0 * vbar[(size_t)r0 * DD + d];
        acc += w1 * vbar[(size_t)r1 * DD + d];
        acc += w2 * vbar[(size_t)r2 * DD + d];
        acc += w3 * vbar[(size_t)r3 * DD + d];
    }
    for (; i < e; ++i)
        acc += valbuf[i] * vbar[(size_t)rowbuf[i] * DD + d];
    out[(size_t)n * DD + d] += acc;
}

// ---------------------------------------------------------------------------
extern "C" void kernel_launch(void* const* d_in, const int* in_sizes, int n_in,
                              void* d_out, int out_size, void* d_ws, size_t ws_size,
                              hipStream_t stream)
{
    (void)in_sizes; (void)n_in; (void)out_size; (void)ws_size;
    const float* Xq = (const float*)d_in[0];
    const float* Xs = (const float*)d_in[1];
    const float* ew = (const float*)d_in[2];
    const float* Wq = (const float*)d_in[3];
    const float* bq = (const float*)d_in[4];
    const float* Wk = (const float*)d_in[5];
    const float* bk = (const float*)d_in[6];
    const float* Wv = (const float*)d_in[7];
    const float* bv = (const float*)d_in[8];
    const int* n_nodes = (const int*)d_in[9];
    const int* ei = (const int*)d_in[10];
    float* out = (float*)d_out;
    float* ws  = (float*)d_ws;

    // workspace layout (float units)
    const size_t OFF_Q      = 0;
    const size_t OFF_K      = (size_t)NN * HD;
    const size_t OFF_V      = OFF_K * 2;
    const size_t OFF_SS     = OFF_K * 3;               // 16 floats
    // zeroed region: deg, cursor, kv, ksum, vsum (contiguous)
    const size_t OFF_DEG    = OFF_SS + 16;             // NN ints
    const size_t OFF_CUR    = OFF_DEG + NN;            // NN ints
    const size_t OFF_KV     = OFF_CUR + NN;            // BB*HH*4096
    const size_t OFF_KSUM   = OFF_KV + (size_t)BB * HH * DD * DD;
    const size_t OFF_VSUM   = OFF_KSUM + (size_t)BB * HH * DD;
    const size_t ZERO_LEN   = (OFF_VSUM + (size_t)BB * HH * DD) - OFF_DEG;
    // non-zeroed: offsets, rowbuf, valbuf, vbar
    const size_t OFF_OFFS   = OFF_VSUM + (size_t)BB * HH * DD;  // NN+1 (+pad)
    const size_t OFF_ROWB   = OFF_OFFS + NN + 16;      // EE ints
    const size_t OFF_VALB   = OFF_ROWB + EE;           // EE floats
    const size_t OFF_VBAR   = OFF_VALB + EE;           // NN*DD
    // total ≈ 96 MB + 16.5 MB ≈ 112.6 MB

    float* q      = ws + OFF_Q;
    float* k      = ws + OFF_K;
    float* v      = ws + OFF_V;
    float* sumsq  = ws + OFF_SS;
    ushort* WT    = (ushort*)(ws + OFF_DEG);           // aliases deg/cursor: dead after gemm
    int*   deg    = (int*)(ws + OFF_DEG);
    int*   cursor = (int*)(ws + OFF_CUR);
    float* kv_s   = ws + OFF_KV;
    float* ksum_s = ws + OFF_KSUM;
    float* vsum_s = ws + OFF_VSUM;
    int*   offs   = (int*)(ws + OFF_OFFS);
    int*   rowbuf = (int*)(ws + OFF_ROWB);
    float* valbuf = ws + OFF_VALB;
    float* vbar   = ws + OFF_VBAR;

    hipMemsetAsync(sumsq, 0, 16 * sizeof(float), stream);
    convert_w<<<768, 256, 0, stream>>>(Wq, Wk, Wv, WT);
    qkv_gemm<<<dim3(2, 256, 3), 256, 0, stream>>>(
        Xq, Xs, WT, bq, bk, bv, q, k, v, sumsq);
    // WT dead; zero deg+cursor+kv+ksum+vsum
    hipMemsetAsync(ws + OFF_DEG, 0, ZERO_LEN * sizeof(float), stream);
    deg_kernel<<<EE / 256, 256, 0, stream>>>(ei, deg);
    scan_kernel<<<1, 1024, 0, stream>>>(deg, offs);
    bucket_kernel<<<EE / 256, 256, 0, stream>>>(ei, ew, deg, offs, cursor, rowbuf, valbuf);
    kv_kernel<<<dim3(HH, BB, 8), 256, 0, stream>>>(k, v, kv_s, ksum_s, vsum_s);
    vbar_kernel<<<(NN * DD) / 256, 256, 0, stream>>>(v, vbar);
    attn_kernel<<<dim3(MM / 64, BB), 256, 0, stream>>>(
        q, kv_s, ksum_s, vsum_s, sumsq, n_nodes, out);
    gcn_gather<<<(NN * DD) / 256, 256, 0, stream>>>(offs, rowbuf, valbuf, vbar, out);
}

// Round 5
// 315.018 us; speedup vs baseline: 1.7447x; 1.2658x over previous
//
#include <hip/hip_runtime.h>

#define NN 32768   // nodes
#define BB 64      // graphs
#define MM 512     // nodes per graph
#define HH 4       // heads
#define DD 64      // head dim
#define INF 256    // input features
#define HD 256     // H*D
#define EE 524288  // edges

typedef unsigned short ushort;
typedef unsigned int uint;
typedef short s16x8 __attribute__((ext_vector_type(8)));
typedef ushort u16x8 __attribute__((ext_vector_type(8)));
typedef float f32x4 __attribute__((ext_vector_type(4)));

__device__ __forceinline__ ushort f2bf(float f) {
    uint u = __float_as_uint(f);
    return (ushort)((u + 0x7fffu + ((u >> 16) & 1u)) >> 16);
}

// ---------------------------------------------------------------------------
// Convert 3 weight matrices [K=256][N=256] fp32 -> transposed bf16 [N][K].
// ---------------------------------------------------------------------------
__global__ __launch_bounds__(256) void convert_w(
    const float* __restrict__ Wq, const float* __restrict__ Wk,
    const float* __restrict__ Wv, ushort* __restrict__ WT)
{
    const int id = blockIdx.x * 256 + threadIdx.x;   // 3*65536 total
    const int mat = id >> 16, rem = id & 65535;
    const int n = rem >> 8, kk = rem & 255;
    const float* W = (mat == 0) ? Wq : (mat == 1) ? Wk : Wv;
    WT[id] = f2bf(W[kk * 256 + n]);  // WT[mat][n][kk]
}

// ---------------------------------------------------------------------------
// bf16 MFMA GEMM: C = A @ W + bias  (z selects q/k/v). Tile 128x128, BK=32.
// ---------------------------------------------------------------------------
#define BKP 40
__global__ __launch_bounds__(256) void qkv_gemm(
    const float* __restrict__ Xq, const float* __restrict__ Xs,
    const ushort* __restrict__ WT,
    const float* __restrict__ bq, const float* __restrict__ bk,
    const float* __restrict__ bv,
    float* __restrict__ qo, float* __restrict__ ko, float* __restrict__ vo,
    float* __restrict__ sumsq)
{
    const int which = blockIdx.z;
    const float* A    = (which == 0) ? Xq : Xs;
    const ushort* W   = WT + (size_t)which * 65536;
    const float* bias = (which == 0) ? bq : (which == 1) ? bk : bv;
    float* C          = (which == 0) ? qo : (which == 1) ? ko : vo;

    __shared__ ushort Asu[128 * BKP];
    __shared__ ushort Bsu[128 * BKP];
    __shared__ float wred[4];

    const int t = threadIdx.x;
    const int l = t & 63, w = t >> 6;
    const int row0 = blockIdx.y * 128;
    const int col0 = blockIdx.x * 128;
    const int wr = (w & 1) * 64, wc = (w >> 1) * 64;
    const int sr = t >> 1, sh = (t & 1) * 16;

    f32x4 acc[4][4] = {};

    for (int k0 = 0; k0 < INF; k0 += 32) {
        const float* ap = &A[(size_t)(row0 + sr) * INF + k0 + sh];
        float4 a0 = *(const float4*)(ap + 0);
        float4 a1 = *(const float4*)(ap + 4);
        float4 a2 = *(const float4*)(ap + 8);
        float4 a3 = *(const float4*)(ap + 12);
        const ushort* bp = &W[(size_t)(col0 + sr) * INF + k0 + sh];
        u16x8 b0 = *(const u16x8*)(bp + 0);
        u16x8 b1 = *(const u16x8*)(bp + 8);

        __syncthreads();
        u16x8 pa0, pa1;
        pa0[0] = f2bf(a0.x); pa0[1] = f2bf(a0.y); pa0[2] = f2bf(a0.z); pa0[3] = f2bf(a0.w);
        pa0[4] = f2bf(a1.x); pa0[5] = f2bf(a1.y); pa0[6] = f2bf(a1.z); pa0[7] = f2bf(a1.w);
        pa1[0] = f2bf(a2.x); pa1[1] = f2bf(a2.y); pa1[2] = f2bf(a2.z); pa1[3] = f2bf(a2.w);
        pa1[4] = f2bf(a3.x); pa1[5] = f2bf(a3.y); pa1[6] = f2bf(a3.z); pa1[7] = f2bf(a3.w);
        *(u16x8*)&Asu[sr * BKP + sh] = pa0;
        *(u16x8*)&Asu[sr * BKP + sh + 8] = pa1;
        *(u16x8*)&Bsu[sr * BKP + sh] = b0;
        *(u16x8*)&Bsu[sr * BKP + sh + 8] = b1;
        __syncthreads();

        const int fr = l & 15, kg = (l >> 4) * 8;
        s16x8 af[4], bf[4];
#pragma unroll
        for (int i = 0; i < 4; ++i)
            af[i] = *(const s16x8*)&Asu[(wr + i * 16 + fr) * BKP + kg];
#pragma unroll
        for (int j = 0; j < 4; ++j)
            bf[j] = *(const s16x8*)&Bsu[(wc + j * 16 + fr) * BKP + kg];
#pragma unroll
        for (int i = 0; i < 4; ++i)
#pragma unroll
            for (int j = 0; j < 4; ++j)
                acc[i][j] = __builtin_amdgcn_mfma_f32_16x16x32_bf16(
                    af[i], bf[j], acc[i][j], 0, 0, 0);
    }

    float loc = 0.f;
#pragma unroll
    for (int j = 0; j < 4; ++j) {
        const int colg = col0 + wc + j * 16 + (l & 15);
        const float bj = bias[colg];
#pragma unroll
        for (int i = 0; i < 4; ++i) {
            const int rowg = row0 + wr + i * 16 + (l >> 4) * 4;
#pragma unroll
            for (int m = 0; m < 4; ++m) {
                float cv = acc[i][j][m] + bj;
                C[(size_t)(rowg + m) * HD + colg] = cv;
                loc += cv * cv;
            }
        }
    }
    if (which < 2) {
#pragma unroll
        for (int off = 32; off > 0; off >>= 1) loc += __shfl_down(loc, off, 64);
        if (l == 0) wred[w] = loc;
        __syncthreads();
        if (t == 0) atomicAdd(&sumsq[which], wred[0] + wred[1] + wred[2] + wred[3]);
    }
}

// ---------------------------------------------------------------------------
// kv via MFMA. Block = (h, b, z): m-range [z*128, z*128+128). Stage k,v
// transposed+bf16 into LDS [d][m] (pitch 136). 2x2 wave partition: wave w
// owns kv rows [(w&1)*32,+32) x cols [(w>>1)*32,+32) — all indices < 64.
// ksum via B=ones MFMA (waves 0,1); vsum via A=ones MFMA (waves 0,2).
// Non-atomic stores into per-z part buffers; attn sums the 4 parts.
// ---------------------------------------------------------------------------
#define KVP 136   // LDS pitch in ushorts (16B multiple; conflict-free)
__global__ __launch_bounds__(256) void kv_mfma(
    const float* __restrict__ k, const float* __restrict__ v,
    float* __restrict__ kv_p, float* __restrict__ ksum_p, float* __restrict__ vsum_p)
{
    const int h = blockIdx.x, b = blockIdx.y, z = blockIdx.z;
    __shared__ ushort kT[64 * KVP];
    __shared__ ushort vT[64 * KVP];
    const int t = threadIdx.x;
    const int l = t & 63, w = t >> 6;
    const size_t base = (size_t)b * MM * HD + (size_t)h * DD;
    const int m0 = z * 128;

    // ---- staging: 128 threads per matrix; thread covers 2 rows x 32 d ----
    {
        const int mat = t >> 7;            // 0: k, 1: v
        const int u = t & 63;              // row-pair index (0..63)
        const int dhalf = (t >> 6) & 1;    // which 32-d half
        const int r0 = 2 * u;
        const int d0 = dhalf * 32;
        const float* src = mat ? v : k;
        ushort* dst = mat ? vT : kT;
        const float* p0 = &src[base + (size_t)(m0 + r0) * HD + d0];
        const float* p1 = p0 + HD;
        float4 ra[8], rb[8];
#pragma unroll
        for (int i = 0; i < 8; ++i) ra[i] = *(const float4*)(p0 + 4 * i);
#pragma unroll
        for (int i = 0; i < 8; ++i) rb[i] = *(const float4*)(p1 + 4 * i);
#pragma unroll
        for (int i = 0; i < 8; ++i) {
            const float a[4] = {ra[i].x, ra[i].y, ra[i].z, ra[i].w};
            const float c[4] = {rb[i].x, rb[i].y, rb[i].z, rb[i].w};
#pragma unroll
            for (int jj = 0; jj < 4; ++jj) {
                const int d = d0 + 4 * i + jj;
                uint pk = (uint)f2bf(a[jj]) | ((uint)f2bf(c[jj]) << 16);
                *(uint*)&dst[d * KVP + r0] = pk;   // rows r0, r0+1 packed
            }
        }
    }
    __syncthreads();

    // ---- MFMA: wave w -> rows [(w&1)*32,+32), cols [(w>>1)*32,+32) ----
    const int fr = l & 15, q4 = l >> 4, kg = q4 * 8;
    const int wr2 = (w & 1) * 32, wc2 = (w >> 1) * 32;
    s16x8 ones;
#pragma unroll
    for (int i = 0; i < 8; ++i) ones[i] = (short)0x3F80;  // bf16 1.0

    f32x4 acc[2][2] = {};
    f32x4 aks[2] = {};
    f32x4 avs[2] = {};
#pragma unroll
    for (int s = 0; s < 4; ++s) {
        const int mo = s * 32 + kg;
        s16x8 af[2], bf[2];
        af[0] = *(const s16x8*)&kT[(wr2 + fr) * KVP + mo];
        af[1] = *(const s16x8*)&kT[(wr2 + 16 + fr) * KVP + mo];
        bf[0] = *(const s16x8*)&vT[(wc2 + fr) * KVP + mo];
        bf[1] = *(const s16x8*)&vT[(wc2 + 16 + fr) * KVP + mo];
#pragma unroll
        for (int il = 0; il < 2; ++il)
#pragma unroll
            for (int jl = 0; jl < 2; ++jl)
                acc[il][jl] = __builtin_amdgcn_mfma_f32_16x16x32_bf16(
                    af[il], bf[jl], acc[il][jl], 0, 0, 0);
#pragma unroll
        for (int il = 0; il < 2; ++il)
            aks[il] = __builtin_amdgcn_mfma_f32_16x16x32_bf16(
                af[il], ones, aks[il], 0, 0, 0);
#pragma unroll
        for (int jl = 0; jl < 2; ++jl)
            avs[jl] = __builtin_amdgcn_mfma_f32_16x16x32_bf16(
                ones, bf[jl], avs[jl], 0, 0, 0);
    }

    // ---- stores (non-atomic, per-z part buffers; all indices < 64) ----
    float* kvb = &kv_p[(((size_t)b * HH + h) * 4 + z) * 4096];
#pragma unroll
    for (int il = 0; il < 2; ++il) {
        const int dkb = wr2 + 16 * il + q4 * 4;
#pragma unroll
        for (int jl = 0; jl < 2; ++jl) {
            const int dv = wc2 + 16 * jl + fr;
#pragma unroll
            for (int m = 0; m < 4; ++m)
                kvb[(size_t)(dkb + m) * 64 + dv] = acc[il][jl][m];
        }
    }
    float* ksb = &ksum_p[(((size_t)b * HH + h) * 4 + z) * 64];
    float* vsb = &vsum_p[(((size_t)b * HH + h) * 4 + z) * 64];
    if (wc2 == 0 && fr == 0) {  // waves 0,1: ksum rows [wr2, wr2+32)
#pragma unroll
        for (int il = 0; il < 2; ++il)
#pragma unroll
            for (int m = 0; m < 4; ++m)
                ksb[wr2 + 16 * il + q4 * 4 + m] = aks[il][m];
    }
    if (wr2 == 0 && l < 16) {   // waves 0,2: vsum cols [wc2, wc2+32)
        vsb[wc2 + l]      = avs[0][0];
        vsb[wc2 + 16 + l] = avs[1][0];
    }
}

// ---------------------------------------------------------------------------
__global__ __launch_bounds__(256) void vbar_kernel(
    const float* __restrict__ v, float* __restrict__ vbar)
{
    const int idx = blockIdx.x * 256 + threadIdx.x;
    const int n = idx >> 6, d = idx & 63;
    const float* vr = &v[(size_t)n * HD + d];
    vbar[idx] = 0.25f * (vr[0] + vr[64] + vr[128] + vr[192]);
}

// ---------------------------------------------------------------------------
__global__ __launch_bounds__(256) void deg_kernel(
    const int* __restrict__ ei, int* __restrict__ deg)
{
    const int e = blockIdx.x * 256 + threadIdx.x;
    if (e < EE) atomicAdd(&deg[ei[EE + e]], 1);
}

// ---------------------------------------------------------------------------
// Exclusive prefix sum of deg[NN] -> offsets[NN+1]. One block, 1024 threads.
// ---------------------------------------------------------------------------
__global__ __launch_bounds__(1024) void scan_kernel(
    const int* __restrict__ deg, int* __restrict__ offsets)
{
    __shared__ int part[1024];
    const int tid = threadIdx.x;
    const int base = tid * 32;
    int loc[32];
    int s = 0;
#pragma unroll
    for (int i = 0; i < 32; ++i) { loc[i] = s; s += deg[base + i]; }
    part[tid] = s;
    __syncthreads();
    for (int off = 1; off < 1024; off <<= 1) {
        int a = part[tid];
        int b2 = (tid >= off) ? part[tid - off] : 0;
        __syncthreads();
        part[tid] = a + b2;
        __syncthreads();
    }
    const int prev = (tid == 0) ? 0 : part[tid - 1];
#pragma unroll
    for (int i = 0; i < 32; ++i) offsets[base + i] = prev + loc[i];
    if (tid == 1023) offsets[NN] = prev + s;
}

// ---------------------------------------------------------------------------
__global__ __launch_bounds__(256) void bucket_kernel(
    const int* __restrict__ ei, const float* __restrict__ ew,
    const int* __restrict__ deg, const int* __restrict__ offsets,
    int* __restrict__ cursor, int* __restrict__ rowbuf, float* __restrict__ valbuf)
{
    const int e = blockIdx.x * 256 + threadIdx.x;
    if (e >= EE) return;
    const int row = ei[e], col = ei[EE + e];
    const long long prod = (long long)deg[row] * (long long)deg[col];
    float val = 0.f;
    if (prod > 0) val = ew[e] * __frsqrt_rn((float)prod);
    const int pos = atomicAdd(&cursor[col], 1);
    const int idx = offsets[col] + pos;
    rowbuf[idx] = row;
    valbuf[idx] = val;
}

// ---------------------------------------------------------------------------
// attn: out[n][d] = (1/H) * sum_h (inv*q·KV + vsum) / (inv*q·KS + n_nodes)
// KV/KS/VS are summed from the 4 z-parts while staging.
// ---------------------------------------------------------------------------
__global__ __launch_bounds__(256) void attn_kernel(
    const float* __restrict__ q, const float* __restrict__ kv_p,
    const float* __restrict__ ksum_p, const float* __restrict__ vsum_p,
    const float* __restrict__ sumsq,
    const int* __restrict__ n_nodes, float* __restrict__ out)
{
    const int b = blockIdx.y;
    const int m0 = blockIdx.x * 64;
    const int tid = threadIdx.x;
    const int tx = tid & 15, ty = tid >> 4;

    __shared__ float qsT[64][68];
    __shared__ float kvs[4096];
    __shared__ float ksum_l[64], vsum_l[64], denom_l[64];

    float acc[4][4] = {};
    const float nn = (float)n_nodes[b];
    const float inv = 1.0f / (sqrtf(sumsq[0]) * sqrtf(sumsq[1]));

    for (int h = 0; h < HH; ++h) {
        __syncthreads();
        {
            const int r = tid >> 2, c0 = (tid & 3) << 4;
            const float* qrow = &q[((size_t)(b * MM + m0 + r)) * HD + h * DD];
#pragma unroll
            for (int jj = 0; jj < 4; ++jj) {
                float4 t4 = *(const float4*)&qrow[c0 + (jj << 2)];
                qsT[c0 + (jj << 2) + 0][r] = t4.x;
                qsT[c0 + (jj << 2) + 1][r] = t4.y;
                qsT[c0 + (jj << 2) + 2][r] = t4.z;
                qsT[c0 + (jj << 2) + 3][r] = t4.w;
            }
        }
        {
            const float* kvg = &kv_p[(((size_t)b * HH + h) * 4) * 4096];
#pragma unroll
            for (int c = 0; c < 4; ++c) {
                const int idx = c * 1024 + (tid << 2);
                float4 s0 = *(const float4*)&kvg[idx];
                float4 s1 = *(const float4*)&kvg[4096 + idx];
                float4 s2 = *(const float4*)&kvg[8192 + idx];
                float4 s3 = *(const float4*)&kvg[12288 + idx];
                *(float4*)&kvs[idx] = make_float4(
                    s0.x + s1.x + s2.x + s3.x, s0.y + s1.y + s2.y + s3.y,
                    s0.z + s1.z + s2.z + s3.z, s0.w + s1.w + s2.w + s3.w);
            }
        }
        if (tid < 64) {
            const float* ksb = &ksum_p[(((size_t)b * HH + h) * 4) * 64];
            ksum_l[tid] = ksb[tid] + ksb[64 + tid] + ksb[128 + tid] + ksb[192 + tid];
        } else if (tid < 128) {
            const float* vsb = &vsum_p[(((size_t)b * HH + h) * 4) * 64];
            const int d = tid - 64;
            vsum_l[d] = vsb[d] + vsb[64 + d] + vsb[128 + d] + vsb[192 + d];
        }
        __syncthreads();

        if (tid < 64) {
            float dsum = 0.f;
#pragma unroll 8
            for (int kk = 0; kk < 64; ++kk) dsum += qsT[kk][tid] * ksum_l[kk];
            denom_l[tid] = nn + inv * dsum;
        }
        __syncthreads();

        float dot[4][4] = {};
#pragma unroll 8
        for (int kk = 0; kk < 64; ++kk) {
            float4 av  = *(const float4*)&qsT[kk][ty << 2];
            float4 bv4 = *(const float4*)&kvs[kk * 64 + (tx << 2)];
            float a[4] = {av.x, av.y, av.z, av.w};
            float bvals[4] = {bv4.x, bv4.y, bv4.z, bv4.w};
#pragma unroll
            for (int i = 0; i < 4; ++i)
#pragma unroll
                for (int j = 0; j < 4; ++j)
                    dot[i][j] = fmaf(a[i], bvals[j], dot[i][j]);
        }
        float rden[4];
#pragma unroll
        for (int i = 0; i < 4; ++i) rden[i] = 0.25f / denom_l[(ty << 2) + i];
#pragma unroll
        for (int i = 0; i < 4; ++i)
#pragma unroll
            for (int j = 0; j < 4; ++j)
                acc[i][j] += (inv * dot[i][j] + vsum_l[(tx << 2) + j]) * rden[i];
    }

#pragma unroll
    for (int i = 0; i < 4; ++i) {
        const size_t node = (size_t)b * MM + m0 + (ty << 2) + i;
        *(float4*)&out[node * DD + (tx << 2)] =
            make_float4(acc[i][0], acc[i][1], acc[i][2], acc[i][3]);
    }
}

// ---------------------------------------------------------------------------
// GCN gather: one wave per destination node; lane = feature. No atomics.
// ---------------------------------------------------------------------------
__global__ __launch_bounds__(256) void gcn_gather(
    const int* __restrict__ offsets, const int* __restrict__ rowbuf,
    const float* __restrict__ valbuf, const float* __restrict__ vbar,
    float* __restrict__ out)
{
    const int t = blockIdx.x * 256 + threadIdx.x;
    const int n = t >> 6, d = t & 63;
    const int s = offsets[n], e = offsets[n + 1];
    float acc = 0.f;
    int i = s;
    for (; i + 4 <= e; i += 4) {
        const int r0 = rowbuf[i], r1 = rowbuf[i + 1], r2 = rowbuf[i + 2], r3 = rowbuf[i + 3];
        const float w0 = valbuf[i], w1 = valbuf[i + 1], w2 = valbuf[i + 2], w3 = valbuf[i + 3];
        acc += w0 * vbar[(size_t)r0 * DD + d];
        acc += w1 * vbar[(size_t)r1 * DD + d];
        acc += w2 * vbar[(size_t)r2 * DD + d];
        acc += w3 * vbar[(size_t)r3 * DD + d];
    }
    for (; i < e; ++i)
        acc += valbuf[i] * vbar[(size_t)rowbuf[i] * DD + d];
    out[(size_t)n * DD + d] += acc;
}

// ---------------------------------------------------------------------------
extern "C" void kernel_launch(void* const* d_in, const int* in_sizes, int n_in,
                              void* d_out, int out_size, void* d_ws, size_t ws_size,
                              hipStream_t stream)
{
    (void)in_sizes; (void)n_in; (void)out_size; (void)ws_size;
    const float* Xq = (const float*)d_in[0];
    const float* Xs = (const float*)d_in[1];
    const float* ew = (const float*)d_in[2];
    const float* Wq = (const float*)d_in[3];
    const float* bq = (const float*)d_in[4];
    const float* Wk = (const float*)d_in[5];
    const float* bk = (const float*)d_in[6];
    const float* Wv = (const float*)d_in[7];
    const float* bv = (const float*)d_in[8];
    const int* n_nodes = (const int*)d_in[9];
    const int* ei = (const int*)d_in[10];
    float* out = (float*)d_out;
    float* ws  = (float*)d_ws;

    // workspace layout (float units)
    const size_t OFF_Q      = 0;
    const size_t OFF_K      = (size_t)NN * HD;
    const size_t OFF_V      = OFF_K * 2;
    const size_t OFF_SS     = OFF_K * 3;               // 16 floats
    const size_t OFF_DEG    = OFF_SS + 16;             // NN ints (zeroed)
    const size_t OFF_CUR    = OFF_DEG + NN;            // NN ints (zeroed)
    const size_t OFF_KV     = OFF_CUR + NN;            // BB*HH*4*4096 (parts)
    const size_t OFF_KSUM   = OFF_KV + (size_t)BB * HH * 4 * 4096;
    const size_t OFF_VSUM   = OFF_KSUM + (size_t)BB * HH * 4 * 64;
    const size_t OFF_OFFS   = OFF_VSUM + (size_t)BB * HH * 4 * 64;  // NN+1
    const size_t OFF_ROWB   = OFF_OFFS + NN + 16;      // EE ints
    const size_t OFF_VALB   = OFF_ROWB + EE;           // EE floats
    const size_t OFF_VBAR   = OFF_VALB + EE;           // NN*DD
    // total ≈ 131 MB

    float* q      = ws + OFF_Q;
    float* k      = ws + OFF_K;
    float* v      = ws + OFF_V;
    float* sumsq  = ws + OFF_SS;
    ushort* WT    = (ushort*)(ws + OFF_DEG);  // aliases deg/cursor/kv-start: dead after gemm
    int*   deg    = (int*)(ws + OFF_DEG);
    int*   cursor = (int*)(ws + OFF_CUR);
    float* kv_p   = ws + OFF_KV;
    float* ksum_p = ws + OFF_KSUM;
    float* vsum_p = ws + OFF_VSUM;
    int*   offs   = (int*)(ws + OFF_OFFS);
    int*   rowbuf = (int*)(ws + OFF_ROWB);
    float* valbuf = ws + OFF_VALB;
    float* vbar   = ws + OFF_VBAR;

    hipMemsetAsync(sumsq, 0, 16 * sizeof(float), stream);
    convert_w<<<768, 256, 0, stream>>>(Wq, Wk, Wv, WT);
    qkv_gemm<<<dim3(2, 256, 3), 256, 0, stream>>>(
        Xq, Xs, WT, bq, bk, bv, q, k, v, sumsq);
    // WT dead; zero deg + cursor only (kv parts are fully overwritten)
    hipMemsetAsync(ws + OFF_DEG, 0, 2 * NN * sizeof(int), stream);
    deg_kernel<<<EE / 256, 256, 0, stream>>>(ei, deg);
    scan_kernel<<<1, 1024, 0, stream>>>(deg, offs);
    bucket_kernel<<<EE / 256, 256, 0, stream>>>(ei, ew, deg, offs, cursor, rowbuf, valbuf);
    kv_mfma<<<dim3(HH, BB, 4), 256, 0, stream>>>(k, v, kv_p, ksum_p, vsum_p);
    vbar_kernel<<<(NN * DD) / 256, 256, 0, stream>>>(v, vbar);
    attn_kernel<<<dim3(MM / 64, BB), 256, 0, stream>>>(
        q, kv_p, ksum_p, vsum_p, sumsq, n_nodes, out);
    gcn_gather<<<(NN * DD) / 256, 256, 0, stream>>>(offs, rowbuf, valbuf, vbar, out);
}

// Round 6
// 308.944 us; speedup vs baseline: 1.7790x; 1.0197x over previous
//
#include <hip/hip_runtime.h>

#define NN 32768   // nodes
#define BB 64      // graphs
#define MM 512     // nodes per graph
#define HH 4       // heads
#define DD 64      // head dim
#define INF 256    // input features
#define HD 256     // H*D
#define EE 524288  // edges

typedef unsigned short ushort;
typedef unsigned int uint;
typedef short s16x8 __attribute__((ext_vector_type(8)));
typedef ushort u16x8 __attribute__((ext_vector_type(8)));
typedef ushort u16x4 __attribute__((ext_vector_type(4)));
typedef float f32x4 __attribute__((ext_vector_type(4)));

__device__ __forceinline__ ushort f2bf(float f) {
    uint u = __float_as_uint(f);
    return (ushort)((u + 0x7fffu + ((u >> 16) & 1u)) >> 16);
}
__device__ __forceinline__ float bf2f(ushort u) {
    return __uint_as_float((uint)u << 16);
}

// ---------------------------------------------------------------------------
// Convert 3 weight matrices [K=256][N=256] fp32 -> transposed bf16 [N][K].
// ---------------------------------------------------------------------------
__global__ __launch_bounds__(256) void convert_w(
    const float* __restrict__ Wq, const float* __restrict__ Wk,
    const float* __restrict__ Wv, ushort* __restrict__ WT)
{
    const int id = blockIdx.x * 256 + threadIdx.x;   // 3*65536 total
    const int mat = id >> 16, rem = id & 65535;
    const int n = rem >> 8, kk = rem & 255;
    const float* W = (mat == 0) ? Wq : (mat == 1) ? Wk : Wv;
    WT[id] = f2bf(W[kk * 256 + n]);  // WT[mat][n][kk]
}

// ---------------------------------------------------------------------------
// bf16 MFMA GEMM, outputs bf16. 1-D grid of 1536 with XCD swizzle: the 6
// col-tiles (2 q from Xq, 2 k + 2 v from Xs) of a row-group land on the same
// XCD so Xs is fetched once. Epilogue repacks the 64x64 wave tile through
// LDS for 128B-coalesced bf16 stores; sumsq from fp32 pre-round values.
// ---------------------------------------------------------------------------
#define BKP 40    // K-loop LDS pitch (ushorts)
#define CP  72    // epilogue LDS pitch (ushorts; 144B rows, b64-aligned)
__global__ __launch_bounds__(256) void qkv_gemm(
    const float* __restrict__ Xq, const float* __restrict__ Xs,
    const ushort* __restrict__ WT,
    const float* __restrict__ bq, const float* __restrict__ bk,
    const float* __restrict__ bv,
    ushort* __restrict__ qo, ushort* __restrict__ ko, ushort* __restrict__ vo,
    float* __restrict__ sumsq)
{
    __shared__ ushort smem_u[4 * 64 * CP];   // 36864 B; aliases Asu/Bsu & Cs
    __shared__ float wred[4];
    ushort* Asu = smem_u;
    ushort* Bsu = smem_u + 128 * BKP;

    const int id = blockIdx.x;
    const int vv = (id & 7) * 192 + (id >> 3);   // XCD-contiguous row-groups
    const int rt = vv / 6, ct = vv % 6;
    const int wsel = ct >> 1;                    // 0:q 1:k 2:v
    const float* A    = (wsel == 0) ? Xq : Xs;
    const ushort* W   = WT + (size_t)wsel * 65536;
    const float* bias = (wsel == 0) ? bq : (wsel == 1) ? bk : bv;
    ushort* C         = (wsel == 0) ? qo : (wsel == 1) ? ko : vo;
    const int row0 = rt * 128;
    const int col0 = (ct & 1) * 128;

    const int t = threadIdx.x;
    const int l = t & 63, w = t >> 6;
    const int fr = l & 15, q4 = l >> 4;
    const int wr = (w & 1) * 64, wc = (w >> 1) * 64;
    const int sr = t >> 1, sh = (t & 1) * 16;

    f32x4 acc[4][4] = {};

    for (int k0 = 0; k0 < INF; k0 += 32) {
        const float* ap = &A[(size_t)(row0 + sr) * INF + k0 + sh];
        float4 a0 = *(const float4*)(ap + 0);
        float4 a1 = *(const float4*)(ap + 4);
        float4 a2 = *(const float4*)(ap + 8);
        float4 a3 = *(const float4*)(ap + 12);
        const ushort* bp = &W[(size_t)(col0 + sr) * INF + k0 + sh];
        u16x8 b0 = *(const u16x8*)(bp + 0);
        u16x8 b1 = *(const u16x8*)(bp + 8);

        __syncthreads();
        u16x8 pa0, pa1;
        pa0[0] = f2bf(a0.x); pa0[1] = f2bf(a0.y); pa0[2] = f2bf(a0.z); pa0[3] = f2bf(a0.w);
        pa0[4] = f2bf(a1.x); pa0[5] = f2bf(a1.y); pa0[6] = f2bf(a1.z); pa0[7] = f2bf(a1.w);
        pa1[0] = f2bf(a2.x); pa1[1] = f2bf(a2.y); pa1[2] = f2bf(a2.z); pa1[3] = f2bf(a2.w);
        pa1[4] = f2bf(a3.x); pa1[5] = f2bf(a3.y); pa1[6] = f2bf(a3.z); pa1[7] = f2bf(a3.w);
        *(u16x8*)&Asu[sr * BKP + sh] = pa0;
        *(u16x8*)&Asu[sr * BKP + sh + 8] = pa1;
        *(u16x8*)&Bsu[sr * BKP + sh] = b0;
        *(u16x8*)&Bsu[sr * BKP + sh + 8] = b1;
        __syncthreads();

        const int kg = q4 * 8;
        s16x8 af[4], bf[4];
#pragma unroll
        for (int i = 0; i < 4; ++i)
            af[i] = *(const s16x8*)&Asu[(wr + i * 16 + fr) * BKP + kg];
#pragma unroll
        for (int j = 0; j < 4; ++j)
            bf[j] = *(const s16x8*)&Bsu[(wc + j * 16 + fr) * BKP + kg];
#pragma unroll
        for (int i = 0; i < 4; ++i)
#pragma unroll
            for (int j = 0; j < 4; ++j)
                acc[i][j] = __builtin_amdgcn_mfma_f32_16x16x32_bf16(
                    af[i], bf[j], acc[i][j], 0, 0, 0);
    }

    // epilogue: bias + sumsq, bf16 repack via LDS, coalesced stores
    __syncthreads();   // all waves done with Asu/Bsu before Cs overwrite
    ushort* cs = smem_u + w * (64 * CP);
    float loc = 0.f;
#pragma unroll
    for (int j = 0; j < 4; ++j) {
        const float bj = bias[col0 + wc + j * 16 + fr];
#pragma unroll
        for (int i = 0; i < 4; ++i) {
#pragma unroll
            for (int m = 0; m < 4; ++m) {
                float cv = acc[i][j][m] + bj;
                loc += cv * cv;
                cs[(i * 16 + q4 * 4 + m) * CP + j * 16 + fr] = f2bf(cv);
            }
        }
    }
    const int srow = l >> 3, scol8 = (l & 7) * 8;
#pragma unroll
    for (int r2 = 0; r2 < 8; ++r2) {
        const int row = r2 * 8 + srow;
        u16x4 lo = *(const u16x4*)&cs[row * CP + scol8];
        u16x4 hi = *(const u16x4*)&cs[row * CP + scol8 + 4];
        u16x8 val;
#pragma unroll
        for (int jj = 0; jj < 4; ++jj) { val[jj] = lo[jj]; val[4 + jj] = hi[jj]; }
        *(u16x8*)&C[(size_t)(row0 + wr + row) * HD + col0 + wc + scol8] = val;
    }

    if (wsel < 2) {
#pragma unroll
        for (int off = 32; off > 0; off >>= 1) loc += __shfl_down(loc, off, 64);
        if (l == 0) wred[w] = loc;
        __syncthreads();
        if (t == 0) atomicAdd(&sumsq[wsel], wred[0] + wred[1] + wred[2] + wred[3]);
    }
}

// ---------------------------------------------------------------------------
// kv via MFMA from bf16 k,v. Block = (h, b, z): m-range [z*128, +128).
// 2x2 wave partition; ksum/vsum via ones-operand MFMAs; per-z part buffers.
// ---------------------------------------------------------------------------
#define KVP 136
__global__ __launch_bounds__(256) void kv_mfma(
    const ushort* __restrict__ k16, const ushort* __restrict__ v16,
    float* __restrict__ kv_p, float* __restrict__ ksum_p, float* __restrict__ vsum_p)
{
    const int h = blockIdx.x, b = blockIdx.y, z = blockIdx.z;
    __shared__ ushort kT[64 * KVP];
    __shared__ ushort vT[64 * KVP];
    const int t = threadIdx.x;
    const int l = t & 63, w = t >> 6;
    const size_t base = (size_t)b * MM * HD + (size_t)h * DD;
    const int m0 = z * 128;

    // staging: thread covers 2 rows x 32 d, transposed into LDS [d][m]
    {
        const int mat = t >> 7;
        const int u = t & 63;
        const int dhalf = (t >> 6) & 1;
        const int r0 = 2 * u;
        const int d0 = dhalf * 32;
        const ushort* src = mat ? v16 : k16;
        ushort* dst = mat ? vT : kT;
        const ushort* p0 = &src[base + (size_t)(m0 + r0) * HD + d0];
        const ushort* p1 = p0 + HD;
        u16x8 ra[4], rb[4];
#pragma unroll
        for (int i = 0; i < 4; ++i) ra[i] = *(const u16x8*)(p0 + 8 * i);
#pragma unroll
        for (int i = 0; i < 4; ++i) rb[i] = *(const u16x8*)(p1 + 8 * i);
#pragma unroll
        for (int i = 0; i < 4; ++i)
#pragma unroll
            for (int jj = 0; jj < 8; ++jj) {
                const int d = d0 + 8 * i + jj;
                uint pk = (uint)ra[i][jj] | ((uint)rb[i][jj] << 16);
                *(uint*)&dst[d * KVP + r0] = pk;
            }
    }
    __syncthreads();

    const int fr = l & 15, q4 = l >> 4, kg = q4 * 8;
    const int wr2 = (w & 1) * 32, wc2 = (w >> 1) * 32;
    s16x8 ones;
#pragma unroll
    for (int i = 0; i < 8; ++i) ones[i] = (short)0x3F80;

    f32x4 acc[2][2] = {};
    f32x4 aks[2] = {};
    f32x4 avs[2] = {};
#pragma unroll
    for (int s = 0; s < 4; ++s) {
        const int mo = s * 32 + kg;
        s16x8 af[2], bf[2];
        af[0] = *(const s16x8*)&kT[(wr2 + fr) * KVP + mo];
        af[1] = *(const s16x8*)&kT[(wr2 + 16 + fr) * KVP + mo];
        bf[0] = *(const s16x8*)&vT[(wc2 + fr) * KVP + mo];
        bf[1] = *(const s16x8*)&vT[(wc2 + 16 + fr) * KVP + mo];
#pragma unroll
        for (int il = 0; il < 2; ++il)
#pragma unroll
            for (int jl = 0; jl < 2; ++jl)
                acc[il][jl] = __builtin_amdgcn_mfma_f32_16x16x32_bf16(
                    af[il], bf[jl], acc[il][jl], 0, 0, 0);
#pragma unroll
        for (int il = 0; il < 2; ++il)
            aks[il] = __builtin_amdgcn_mfma_f32_16x16x32_bf16(
                af[il], ones, aks[il], 0, 0, 0);
#pragma unroll
        for (int jl = 0; jl < 2; ++jl)
            avs[jl] = __builtin_amdgcn_mfma_f32_16x16x32_bf16(
                ones, bf[jl], avs[jl], 0, 0, 0);
    }

    float* kvb = &kv_p[(((size_t)b * HH + h) * 4 + z) * 4096];
#pragma unroll
    for (int il = 0; il < 2; ++il) {
        const int dkb = wr2 + 16 * il + q4 * 4;
#pragma unroll
        for (int jl = 0; jl < 2; ++jl) {
            const int dv = wc2 + 16 * jl + fr;
#pragma unroll
            for (int m = 0; m < 4; ++m)
                kvb[(size_t)(dkb + m) * 64 + dv] = acc[il][jl][m];
        }
    }
    float* ksb = &ksum_p[(((size_t)b * HH + h) * 4 + z) * 64];
    float* vsb = &vsum_p[(((size_t)b * HH + h) * 4 + z) * 64];
    if (wc2 == 0 && fr == 0) {
#pragma unroll
        for (int il = 0; il < 2; ++il)
#pragma unroll
            for (int m = 0; m < 4; ++m)
                ksb[wr2 + 16 * il + q4 * 4 + m] = aks[il][m];
    }
    if (wr2 == 0 && l < 16) {
        vsb[wc2 + l]      = avs[0][0];
        vsb[wc2 + 16 + l] = avs[1][0];
    }
}

// ---------------------------------------------------------------------------
__global__ __launch_bounds__(256) void vbar_kernel(
    const ushort* __restrict__ v16, float* __restrict__ vbar)
{
    const int idx = blockIdx.x * 256 + threadIdx.x;
    const int n = idx >> 6, d = idx & 63;
    const ushort* vr = &v16[(size_t)n * HD + d];
    vbar[idx] = 0.25f * (bf2f(vr[0]) + bf2f(vr[64]) + bf2f(vr[128]) + bf2f(vr[192]));
}

// ---------------------------------------------------------------------------
__global__ __launch_bounds__(256) void deg_kernel(
    const int* __restrict__ ei, int* __restrict__ deg)
{
    const int e = blockIdx.x * 256 + threadIdx.x;
    if (e < EE) atomicAdd(&deg[ei[EE + e]], 1);
}

// ---------------------------------------------------------------------------
__global__ __launch_bounds__(1024) void scan_kernel(
    const int* __restrict__ deg, int* __restrict__ offsets)
{
    __shared__ int part[1024];
    const int tid = threadIdx.x;
    const int base = tid * 32;
    int loc[32];
    int s = 0;
#pragma unroll
    for (int i = 0; i < 32; ++i) { loc[i] = s; s += deg[base + i]; }
    part[tid] = s;
    __syncthreads();
    for (int off = 1; off < 1024; off <<= 1) {
        int a = part[tid];
        int b2 = (tid >= off) ? part[tid - off] : 0;
        __syncthreads();
        part[tid] = a + b2;
        __syncthreads();
    }
    const int prev = (tid == 0) ? 0 : part[tid - 1];
#pragma unroll
    for (int i = 0; i < 32; ++i) offsets[base + i] = prev + loc[i];
    if (tid == 1023) offsets[NN] = prev + s;
}

// ---------------------------------------------------------------------------
__global__ __launch_bounds__(256) void bucket_kernel(
    const int* __restrict__ ei, const float* __restrict__ ew,
    const int* __restrict__ deg, const int* __restrict__ offsets,
    int* __restrict__ cursor, int* __restrict__ rowbuf, float* __restrict__ valbuf)
{
    const int e = blockIdx.x * 256 + threadIdx.x;
    if (e >= EE) return;
    const int row = ei[e], col = ei[EE + e];
    const long long prod = (long long)deg[row] * (long long)deg[col];
    float val = 0.f;
    if (prod > 0) val = ew[e] * __frsqrt_rn((float)prod);
    const int pos = atomicAdd(&cursor[col], 1);
    const int idx = offsets[col] + pos;
    rowbuf[idx] = row;
    valbuf[idx] = val;
}

// ---------------------------------------------------------------------------
// attn: out[n][d] = (1/H) * sum_h (inv*q·KV + vsum) / (inv*q·KS + n_nodes)
// q is bf16; KV/KS/VS summed from 4 z-parts while staging.
// ---------------------------------------------------------------------------
__global__ __launch_bounds__(256) void attn_kernel(
    const ushort* __restrict__ q16, const float* __restrict__ kv_p,
    const float* __restrict__ ksum_p, const float* __restrict__ vsum_p,
    const float* __restrict__ sumsq,
    const int* __restrict__ n_nodes, float* __restrict__ out)
{
    const int b = blockIdx.y;
    const int m0 = blockIdx.x * 64;
    const int tid = threadIdx.x;
    const int tx = tid & 15, ty = tid >> 4;

    __shared__ float qsT[64][68];
    __shared__ float kvs[4096];
    __shared__ float ksum_l[64], vsum_l[64], denom_l[64];

    float acc[4][4] = {};
    const float nn = (float)n_nodes[b];
    const float inv = 1.0f / (sqrtf(sumsq[0]) * sqrtf(sumsq[1]));

    for (int h = 0; h < HH; ++h) {
        __syncthreads();
        {
            const int r = tid >> 2, c0 = (tid & 3) << 4;
            const ushort* qrow = &q16[((size_t)(b * MM + m0 + r)) * HD + h * DD];
            u16x8 t0 = *(const u16x8*)&qrow[c0];
            u16x8 t1 = *(const u16x8*)&qrow[c0 + 8];
#pragma unroll
            for (int jj = 0; jj < 8; ++jj) qsT[c0 + jj][r] = bf2f(t0[jj]);
#pragma unroll
            for (int jj = 0; jj < 8; ++jj) qsT[c0 + 8 + jj][r] = bf2f(t1[jj]);
        }
        {
            const float* kvg = &kv_p[(((size_t)b * HH + h) * 4) * 4096];
#pragma unroll
            for (int c = 0; c < 4; ++c) {
                const int idx = c * 1024 + (tid << 2);
                float4 s0 = *(const float4*)&kvg[idx];
                float4 s1 = *(const float4*)&kvg[4096 + idx];
                float4 s2 = *(const float4*)&kvg[8192 + idx];
                float4 s3 = *(const float4*)&kvg[12288 + idx];
                *(float4*)&kvs[idx] = make_float4(
                    s0.x + s1.x + s2.x + s3.x, s0.y + s1.y + s2.y + s3.y,
                    s0.z + s1.z + s2.z + s3.z, s0.w + s1.w + s2.w + s3.w);
            }
        }
        if (tid < 64) {
            const float* ksb = &ksum_p[(((size_t)b * HH + h) * 4) * 64];
            ksum_l[tid] = ksb[tid] + ksb[64 + tid] + ksb[128 + tid] + ksb[192 + tid];
        } else if (tid < 128) {
            const float* vsb = &vsum_p[(((size_t)b * HH + h) * 4) * 64];
            const int d = tid - 64;
            vsum_l[d] = vsb[d] + vsb[64 + d] + vsb[128 + d] + vsb[192 + d];
        }
        __syncthreads();

        if (tid < 64) {
            float dsum = 0.f;
#pragma unroll 8
            for (int kk = 0; kk < 64; ++kk) dsum += qsT[kk][tid] * ksum_l[kk];
            denom_l[tid] = nn + inv * dsum;
        }
        __syncthreads();

        float dot[4][4] = {};
#pragma unroll 8
        for (int kk = 0; kk < 64; ++kk) {
            float4 av  = *(const float4*)&qsT[kk][ty << 2];
            float4 bv4 = *(const float4*)&kvs[kk * 64 + (tx << 2)];
            float a[4] = {av.x, av.y, av.z, av.w};
            float bvals[4] = {bv4.x, bv4.y, bv4.z, bv4.w};
#pragma unroll
            for (int i = 0; i < 4; ++i)
#pragma unroll
                for (int j = 0; j < 4; ++j)
                    dot[i][j] = fmaf(a[i], bvals[j], dot[i][j]);
        }
        float rden[4];
#pragma unroll
        for (int i = 0; i < 4; ++i) rden[i] = 0.25f / denom_l[(ty << 2) + i];
#pragma unroll
        for (int i = 0; i < 4; ++i)
#pragma unroll
            for (int j = 0; j < 4; ++j)
                acc[i][j] += (inv * dot[i][j] + vsum_l[(tx << 2) + j]) * rden[i];
    }

#pragma unroll
    for (int i = 0; i < 4; ++i) {
        const size_t node = (size_t)b * MM + m0 + (ty << 2) + i;
        *(float4*)&out[node * DD + (tx << 2)] =
            make_float4(acc[i][0], acc[i][1], acc[i][2], acc[i][3]);
    }
}

// ---------------------------------------------------------------------------
// GCN gather: one wave per destination node; lane = feature. No atomics.
// ---------------------------------------------------------------------------
__global__ __launch_bounds__(256) void gcn_gather(
    const int* __restrict__ offsets, const int* __restrict__ rowbuf,
    const float* __restrict__ valbuf, const float* __restrict__ vbar,
    float* __restrict__ out)
{
    const int t = blockIdx.x * 256 + threadIdx.x;
    const int n = t >> 6, d = t & 63;
    const int s = offsets[n], e = offsets[n + 1];
    float acc = 0.f;
    int i = s;
    for (; i + 4 <= e; i += 4) {
        const int r0 = rowbuf[i], r1 = rowbuf[i + 1], r2 = rowbuf[i + 2], r3 = rowbuf[i + 3];
        const float w0 = valbuf[i], w1 = valbuf[i + 1], w2 = valbuf[i + 2], w3 = valbuf[i + 3];
        acc += w0 * vbar[(size_t)r0 * DD + d];
        acc += w1 * vbar[(size_t)r1 * DD + d];
        acc += w2 * vbar[(size_t)r2 * DD + d];
        acc += w3 * vbar[(size_t)r3 * DD + d];
    }
    for (; i < e; ++i)
        acc += valbuf[i] * vbar[(size_t)rowbuf[i] * DD + d];
    out[(size_t)n * DD + d] += acc;
}

// ---------------------------------------------------------------------------
extern "C" void kernel_launch(void* const* d_in, const int* in_sizes, int n_in,
                              void* d_out, int out_size, void* d_ws, size_t ws_size,
                              hipStream_t stream)
{
    (void)in_sizes; (void)n_in; (void)out_size; (void)ws_size;
    const float* Xq = (const float*)d_in[0];
    const float* Xs = (const float*)d_in[1];
    const float* ew = (const float*)d_in[2];
    const float* Wq = (const float*)d_in[3];
    const float* bq = (const float*)d_in[4];
    const float* Wk = (const float*)d_in[5];
    const float* bk = (const float*)d_in[6];
    const float* Wv = (const float*)d_in[7];
    const float* bv = (const float*)d_in[8];
    const int* n_nodes = (const int*)d_in[9];
    const int* ei = (const int*)d_in[10];
    float* out = (float*)d_out;
    float* ws  = (float*)d_ws;

    // workspace layout (float units); q/k/v are bf16 (half-float footprint)
    const size_t SZ_QKV  = (size_t)NN * HD / 2;        // 4194304 floats each
    const size_t OFF_Q    = 0;
    const size_t OFF_K    = SZ_QKV;
    const size_t OFF_V    = SZ_QKV * 2;
    const size_t OFF_SS   = SZ_QKV * 3;                // 16 floats
    const size_t OFF_DEG  = OFF_SS + 16;               // NN ints (zeroed)
    const size_t OFF_CUR  = OFF_DEG + NN;              // NN ints (zeroed)
    const size_t OFF_KV   = OFF_CUR + NN;              // BB*HH*4*4096 parts
    const size_t OFF_KSUM = OFF_KV + (size_t)BB * HH * 4 * 4096;
    const size_t OFF_VSUM = OFF_KSUM + (size_t)BB * HH * 4 * 64;
    const size_t OFF_OFFS = OFF_VSUM + (size_t)BB * HH * 4 * 64;  // NN+1
    const size_t OFF_ROWB = OFF_OFFS + NN + 16;        // EE ints
    const size_t OFF_VALB = OFF_ROWB + EE;             // EE floats
    const size_t OFF_VBAR = OFF_VALB + EE;             // NN*DD
    // total ≈ 81 MB

    ushort* q16   = (ushort*)(ws + OFF_Q);
    ushort* k16   = (ushort*)(ws + OFF_K);
    ushort* v16   = (ushort*)(ws + OFF_V);
    float* sumsq  = ws + OFF_SS;
    ushort* WT    = (ushort*)(ws + OFF_DEG);  // aliases deg/cursor: dead after gemm
    int*   deg    = (int*)(ws + OFF_DEG);
    int*   cursor = (int*)(ws + OFF_CUR);
    float* kv_p   = ws + OFF_KV;
    float* ksum_p = ws + OFF_KSUM;
    float* vsum_p = ws + OFF_VSUM;
    int*   offs   = (int*)(ws + OFF_OFFS);
    int*   rowbuf = (int*)(ws + OFF_ROWB);
    float* valbuf = ws + OFF_VALB;
    float* vbar   = ws + OFF_VBAR;

    hipMemsetAsync(sumsq, 0, 16 * sizeof(float), stream);
    convert_w<<<768, 256, 0, stream>>>(Wq, Wk, Wv, WT);
    qkv_gemm<<<1536, 256, 0, stream>>>(
        Xq, Xs, WT, bq, bk, bv, q16, k16, v16, sumsq);
    // WT dead; zero deg + cursor
    hipMemsetAsync(ws + OFF_DEG, 0, 2 * NN * sizeof(int), stream);
    deg_kernel<<<EE / 256, 256, 0, stream>>>(ei, deg);
    scan_kernel<<<1, 1024, 0, stream>>>(deg, offs);
    bucket_kernel<<<EE / 256, 256, 0, stream>>>(ei, ew, deg, offs, cursor, rowbuf, valbuf);
    kv_mfma<<<dim3(HH, BB, 4), 256, 0, stream>>>(k16, v16, kv_p, ksum_p, vsum_p);
    vbar_kernel<<<(NN * DD) / 256, 256, 0, stream>>>(v16, vbar);
    attn_kernel<<<dim3(MM / 64, BB), 256, 0, stream>>>(
        q16, kv_p, ksum_p, vsum_p, sumsq, n_nodes, out);
    gcn_gather<<<(NN * DD) / 256, 256, 0, stream>>>(offs, rowbuf, valbuf, vbar, out);
}

// Round 7
// 306.656 us; speedup vs baseline: 1.7922x; 1.0075x over previous
//
#include <hip/hip_runtime.h>

#define NN 32768   // nodes
#define BB 64      // graphs
#define MM 512     // nodes per graph
#define HH 4       // heads
#define DD 64      // head dim
#define INF 256    // input features
#define HD 256     // H*D
#define EE 524288  // edges

typedef unsigned short ushort;
typedef unsigned int uint;
typedef short s16x8 __attribute__((ext_vector_type(8)));
typedef ushort u16x8 __attribute__((ext_vector_type(8)));
typedef float f32x4 __attribute__((ext_vector_type(4)));

__device__ __forceinline__ ushort f2bf(float f) {
    uint u = __float_as_uint(f);
    return (ushort)((u + 0x7fffu + ((u >> 16) & 1u)) >> 16);
}
__device__ __forceinline__ float bf2f(ushort u) {
    return __uint_as_float((uint)u << 16);
}

// ---------------------------------------------------------------------------
// Convert 3 weight matrices [K=256][N=256] fp32 -> transposed bf16 [N][K].
// ---------------------------------------------------------------------------
__global__ __launch_bounds__(256) void convert_w(
    const float* __restrict__ Wq, const float* __restrict__ Wk,
    const float* __restrict__ Wv, ushort* __restrict__ WT)
{
    const int id = blockIdx.x * 256 + threadIdx.x;   // 3*65536 total
    const int mat = id >> 16, rem = id & 65535;
    const int n = rem >> 8, kk = rem & 255;
    const float* W = (mat == 0) ? Wq : (mat == 1) ? Wk : Wv;
    WT[id] = f2bf(W[kk * 256 + n]);  // WT[mat][n][kk]
}

// ---------------------------------------------------------------------------
// bf16 MFMA GEMM, bf16 outputs. Register-double-buffered K-loop: A/B for
// iter k+1 are loaded into VGPRs during iter k's MFMA phase (issued after
// the barrier so its vmcnt(0) drain doesn't wait on them). Slim epilogue:
// direct bf16 stores (L2 merges 32B segments), no LDS repack -> 18.5 KB LDS.
// XCD swizzle keeps the 6 col-tiles of a row-group on one XCD (Xs reuse).
// ---------------------------------------------------------------------------
#define BKP 40    // A LDS pitch (ushorts)
#define BPI 32    // B LDS pitch (ushorts, unpadded)
__global__ __launch_bounds__(256) void qkv_gemm(
    const float* __restrict__ Xq, const float* __restrict__ Xs,
    const ushort* __restrict__ WT,
    const float* __restrict__ bq, const float* __restrict__ bk,
    const float* __restrict__ bv,
    ushort* __restrict__ qo, ushort* __restrict__ ko, ushort* __restrict__ vo,
    float* __restrict__ sumsq)
{
    __shared__ ushort Asu[128 * BKP];   // 10240 B
    __shared__ ushort Bsu[128 * BPI];   //  8192 B
    __shared__ float wred[4];

    const int id = blockIdx.x;
    const int vv = (id & 7) * 192 + (id >> 3);   // XCD-contiguous row-groups
    const int rt = vv / 6, ct = vv % 6;
    const int wsel = ct >> 1;                    // 0:q 1:k 2:v
    const float* A    = (wsel == 0) ? Xq : Xs;
    const ushort* W   = WT + (size_t)wsel * 65536;
    const float* bias = (wsel == 0) ? bq : (wsel == 1) ? bk : bv;
    ushort* C         = (wsel == 0) ? qo : (wsel == 1) ? ko : vo;
    const int row0 = rt * 128;
    const int col0 = (ct & 1) * 128;

    const int t = threadIdx.x;
    const int l = t & 63, w = t >> 6;
    const int fr = l & 15, q4 = l >> 4;
    const int wr = (w & 1) * 64, wc = (w >> 1) * 64;
    const int sr = t >> 1, sh = (t & 1) * 16;    // A/B staging: row, k-half

    f32x4 acc[4][4] = {};

    // register prefetch buffers
    float4 a0, a1, a2, a3;
    u16x8 b0, b1;
    {
        const float* ap = &A[(size_t)(row0 + sr) * INF + sh];
        a0 = *(const float4*)(ap + 0);
        a1 = *(const float4*)(ap + 4);
        a2 = *(const float4*)(ap + 8);
        a3 = *(const float4*)(ap + 12);
        const ushort* bp = &W[(size_t)(col0 + sr) * INF + sh];
        b0 = *(const u16x8*)(bp + 0);
        b1 = *(const u16x8*)(bp + 8);
    }

    for (int it = 0; it < 8; ++it) {
        __syncthreads();   // previous iteration's fragment reads complete
        {
            u16x8 pa0, pa1;
            pa0[0] = f2bf(a0.x); pa0[1] = f2bf(a0.y); pa0[2] = f2bf(a0.z); pa0[3] = f2bf(a0.w);
            pa0[4] = f2bf(a1.x); pa0[5] = f2bf(a1.y); pa0[6] = f2bf(a1.z); pa0[7] = f2bf(a1.w);
            pa1[0] = f2bf(a2.x); pa1[1] = f2bf(a2.y); pa1[2] = f2bf(a2.z); pa1[3] = f2bf(a2.w);
            pa1[4] = f2bf(a3.x); pa1[5] = f2bf(a3.y); pa1[6] = f2bf(a3.z); pa1[7] = f2bf(a3.w);
            *(u16x8*)&Asu[sr * BKP + sh] = pa0;
            *(u16x8*)&Asu[sr * BKP + sh + 8] = pa1;
            *(u16x8*)&Bsu[sr * BPI + sh] = b0;
            *(u16x8*)&Bsu[sr * BPI + sh + 8] = b1;
        }
        __syncthreads();   // tiles visible (nothing in vmcnt queue here)

        if (it < 7) {      // issue next-iter loads into the MFMA phase
            const int k0 = (it + 1) * 32;
            const float* ap = &A[(size_t)(row0 + sr) * INF + k0 + sh];
            a0 = *(const float4*)(ap + 0);
            a1 = *(const float4*)(ap + 4);
            a2 = *(const float4*)(ap + 8);
            a3 = *(const float4*)(ap + 12);
            const ushort* bp = &W[(size_t)(col0 + sr) * INF + k0 + sh];
            b0 = *(const u16x8*)(bp + 0);
            b1 = *(const u16x8*)(bp + 8);
        }

        const int kg = q4 * 8;
        s16x8 af[4], bf[4];
#pragma unroll
        for (int i = 0; i < 4; ++i)
            af[i] = *(const s16x8*)&Asu[(wr + i * 16 + fr) * BKP + kg];
#pragma unroll
        for (int j = 0; j < 4; ++j)
            bf[j] = *(const s16x8*)&Bsu[(wc + j * 16 + fr) * BPI + kg];
#pragma unroll
        for (int i = 0; i < 4; ++i)
#pragma unroll
            for (int j = 0; j < 4; ++j)
                acc[i][j] = __builtin_amdgcn_mfma_f32_16x16x32_bf16(
                    af[i], bf[j], acc[i][j], 0, 0, 0);
    }

    // epilogue: bias + sumsq + direct bf16 stores (no LDS repack)
    float loc = 0.f;
#pragma unroll
    for (int j = 0; j < 4; ++j) {
        const int colg = col0 + wc + j * 16 + fr;
        const float bj = bias[colg];
#pragma unroll
        for (int i = 0; i < 4; ++i) {
            const int rowg = row0 + wr + i * 16 + q4 * 4;
#pragma unroll
            for (int m = 0; m < 4; ++m) {
                float cv = acc[i][j][m] + bj;
                loc += cv * cv;
                C[(size_t)(rowg + m) * HD + colg] = f2bf(cv);
            }
        }
    }
    if (wsel < 2) {
#pragma unroll
        for (int off = 32; off > 0; off >>= 1) loc += __shfl_down(loc, off, 64);
        if (l == 0) wred[w] = loc;
        __syncthreads();
        if (t == 0) atomicAdd(&sumsq[wsel], wred[0] + wred[1] + wred[2] + wred[3]);
    }
}

// ---------------------------------------------------------------------------
// kv via MFMA from bf16 k,v. Block = (h, b, z): m-range [z*128, +128).
// 2x2 wave partition; ksum/vsum via ones-operand MFMAs; per-z part buffers.
// ---------------------------------------------------------------------------
#define KVP 136
__global__ __launch_bounds__(256) void kv_mfma(
    const ushort* __restrict__ k16, const ushort* __restrict__ v16,
    float* __restrict__ kv_p, float* __restrict__ ksum_p, float* __restrict__ vsum_p)
{
    const int h = blockIdx.x, b = blockIdx.y, z = blockIdx.z;
    __shared__ ushort kT[64 * KVP];
    __shared__ ushort vT[64 * KVP];
    const int t = threadIdx.x;
    const int l = t & 63, w = t >> 6;
    const size_t base = (size_t)b * MM * HD + (size_t)h * DD;
    const int m0 = z * 128;

    {
        const int mat = t >> 7;
        const int u = t & 63;
        const int dhalf = (t >> 6) & 1;
        const int r0 = 2 * u;
        const int d0 = dhalf * 32;
        const ushort* src = mat ? v16 : k16;
        ushort* dst = mat ? vT : kT;
        const ushort* p0 = &src[base + (size_t)(m0 + r0) * HD + d0];
        const ushort* p1 = p0 + HD;
        u16x8 ra[4], rb[4];
#pragma unroll
        for (int i = 0; i < 4; ++i) ra[i] = *(const u16x8*)(p0 + 8 * i);
#pragma unroll
        for (int i = 0; i < 4; ++i) rb[i] = *(const u16x8*)(p1 + 8 * i);
#pragma unroll
        for (int i = 0; i < 4; ++i)
#pragma unroll
            for (int jj = 0; jj < 8; ++jj) {
                const int d = d0 + 8 * i + jj;
                uint pk = (uint)ra[i][jj] | ((uint)rb[i][jj] << 16);
                *(uint*)&dst[d * KVP + r0] = pk;
            }
    }
    __syncthreads();

    const int fr = l & 15, q4 = l >> 4, kg = q4 * 8;
    const int wr2 = (w & 1) * 32, wc2 = (w >> 1) * 32;
    s16x8 ones;
#pragma unroll
    for (int i = 0; i < 8; ++i) ones[i] = (short)0x3F80;

    f32x4 acc[2][2] = {};
    f32x4 aks[2] = {};
    f32x4 avs[2] = {};
#pragma unroll
    for (int s = 0; s < 4; ++s) {
        const int mo = s * 32 + kg;
        s16x8 af[2], bf[2];
        af[0] = *(const s16x8*)&kT[(wr2 + fr) * KVP + mo];
        af[1] = *(const s16x8*)&kT[(wr2 + 16 + fr) * KVP + mo];
        bf[0] = *(const s16x8*)&vT[(wc2 + fr) * KVP + mo];
        bf[1] = *(const s16x8*)&vT[(wc2 + 16 + fr) * KVP + mo];
#pragma unroll
        for (int il = 0; il < 2; ++il)
#pragma unroll
            for (int jl = 0; jl < 2; ++jl)
                acc[il][jl] = __builtin_amdgcn_mfma_f32_16x16x32_bf16(
                    af[il], bf[jl], acc[il][jl], 0, 0, 0);
#pragma unroll
        for (int il = 0; il < 2; ++il)
            aks[il] = __builtin_amdgcn_mfma_f32_16x16x32_bf16(
                af[il], ones, aks[il], 0, 0, 0);
#pragma unroll
        for (int jl = 0; jl < 2; ++jl)
            avs[jl] = __builtin_amdgcn_mfma_f32_16x16x32_bf16(
                ones, bf[jl], avs[jl], 0, 0, 0);
    }

    float* kvb = &kv_p[(((size_t)b * HH + h) * 4 + z) * 4096];
#pragma unroll
    for (int il = 0; il < 2; ++il) {
        const int dkb = wr2 + 16 * il + q4 * 4;
#pragma unroll
        for (int jl = 0; jl < 2; ++jl) {
            const int dv = wc2 + 16 * jl + fr;
#pragma unroll
            for (int m = 0; m < 4; ++m)
                kvb[(size_t)(dkb + m) * 64 + dv] = acc[il][jl][m];
        }
    }
    float* ksb = &ksum_p[(((size_t)b * HH + h) * 4 + z) * 64];
    float* vsb = &vsum_p[(((size_t)b * HH + h) * 4 + z) * 64];
    if (wc2 == 0 && fr == 0) {
#pragma unroll
        for (int il = 0; il < 2; ++il)
#pragma unroll
            for (int m = 0; m < 4; ++m)
                ksb[wr2 + 16 * il + q4 * 4 + m] = aks[il][m];
    }
    if (wr2 == 0 && l < 16) {
        vsb[wc2 + l]      = avs[0][0];
        vsb[wc2 + 16 + l] = avs[1][0];
    }
}

// ---------------------------------------------------------------------------
__global__ __launch_bounds__(256) void vbar_kernel(
    const ushort* __restrict__ v16, float* __restrict__ vbar)
{
    const int idx = blockIdx.x * 256 + threadIdx.x;
    const int n = idx >> 6, d = idx & 63;
    const ushort* vr = &v16[(size_t)n * HD + d];
    vbar[idx] = 0.25f * (bf2f(vr[0]) + bf2f(vr[64]) + bf2f(vr[128]) + bf2f(vr[192]));
}

// ---------------------------------------------------------------------------
__global__ __launch_bounds__(256) void deg_kernel(
    const int* __restrict__ ei, int* __restrict__ deg)
{
    const int e = blockIdx.x * 256 + threadIdx.x;
    if (e < EE) atomicAdd(&deg[ei[EE + e]], 1);
}

// ---------------------------------------------------------------------------
__global__ __launch_bounds__(1024) void scan_kernel(
    const int* __restrict__ deg, int* __restrict__ offsets)
{
    __shared__ int part[1024];
    const int tid = threadIdx.x;
    const int base = tid * 32;
    int loc[32];
    int s = 0;
#pragma unroll
    for (int i = 0; i < 32; ++i) { loc[i] = s; s += deg[base + i]; }
    part[tid] = s;
    __syncthreads();
    for (int off = 1; off < 1024; off <<= 1) {
        int a = part[tid];
        int b2 = (tid >= off) ? part[tid - off] : 0;
        __syncthreads();
        part[tid] = a + b2;
        __syncthreads();
    }
    const int prev = (tid == 0) ? 0 : part[tid - 1];
#pragma unroll
    for (int i = 0; i < 32; ++i) offsets[base + i] = prev + loc[i];
    if (tid == 1023) offsets[NN] = prev + s;
}

// ---------------------------------------------------------------------------
__global__ __launch_bounds__(256) void bucket_kernel(
    const int* __restrict__ ei, const float* __restrict__ ew,
    const int* __restrict__ deg, const int* __restrict__ offsets,
    int* __restrict__ cursor, int* __restrict__ rowbuf, float* __restrict__ valbuf)
{
    const int e = blockIdx.x * 256 + threadIdx.x;
    if (e >= EE) return;
    const int row = ei[e], col = ei[EE + e];
    const long long prod = (long long)deg[row] * (long long)deg[col];
    float val = 0.f;
    if (prod > 0) val = ew[e] * __frsqrt_rn((float)prod);
    const int pos = atomicAdd(&cursor[col], 1);
    const int idx = offsets[col] + pos;
    rowbuf[idx] = row;
    valbuf[idx] = val;
}

// ---------------------------------------------------------------------------
// attn: out[n][d] = (1/H) * sum_h (inv*q·KV + vsum) / (inv*q·KS + n_nodes)
// q is bf16; KV/KS/VS summed from 4 z-parts while staging.
// ---------------------------------------------------------------------------
__global__ __launch_bounds__(256) void attn_kernel(
    const ushort* __restrict__ q16, const float* __restrict__ kv_p,
    const float* __restrict__ ksum_p, const float* __restrict__ vsum_p,
    const float* __restrict__ sumsq,
    const int* __restrict__ n_nodes, float* __restrict__ out)
{
    const int b = blockIdx.y;
    const int m0 = blockIdx.x * 64;
    const int tid = threadIdx.x;
    const int tx = tid & 15, ty = tid >> 4;

    __shared__ float qsT[64][68];
    __shared__ float kvs[4096];
    __shared__ float ksum_l[64], vsum_l[64], denom_l[64];

    float acc[4][4] = {};
    const float nn = (float)n_nodes[b];
    const float inv = 1.0f / (sqrtf(sumsq[0]) * sqrtf(sumsq[1]));

    for (int h = 0; h < HH; ++h) {
        __syncthreads();
        {
            const int r = tid >> 2, c0 = (tid & 3) << 4;
            const ushort* qrow = &q16[((size_t)(b * MM + m0 + r)) * HD + h * DD];
            u16x8 t0 = *(const u16x8*)&qrow[c0];
            u16x8 t1 = *(const u16x8*)&qrow[c0 + 8];
#pragma unroll
            for (int jj = 0; jj < 8; ++jj) qsT[c0 + jj][r] = bf2f(t0[jj]);
#pragma unroll
            for (int jj = 0; jj < 8; ++jj) qsT[c0 + 8 + jj][r] = bf2f(t1[jj]);
        }
        {
            const float* kvg = &kv_p[(((size_t)b * HH + h) * 4) * 4096];
#pragma unroll
            for (int c = 0; c < 4; ++c) {
                const int idx = c * 1024 + (tid << 2);
                float4 s0 = *(const float4*)&kvg[idx];
                float4 s1 = *(const float4*)&kvg[4096 + idx];
                float4 s2 = *(const float4*)&kvg[8192 + idx];
                float4 s3 = *(const float4*)&kvg[12288 + idx];
                *(float4*)&kvs[idx] = make_float4(
                    s0.x + s1.x + s2.x + s3.x, s0.y + s1.y + s2.y + s3.y,
                    s0.z + s1.z + s2.z + s3.z, s0.w + s1.w + s2.w + s3.w);
            }
        }
        if (tid < 64) {
            const float* ksb = &ksum_p[(((size_t)b * HH + h) * 4) * 64];
            ksum_l[tid] = ksb[tid] + ksb[64 + tid] + ksb[128 + tid] + ksb[192 + tid];
        } else if (tid < 128) {
            const float* vsb = &vsum_p[(((size_t)b * HH + h) * 4) * 64];
            const int d = tid - 64;
            vsum_l[d] = vsb[d] + vsb[64 + d] + vsb[128 + d] + vsb[192 + d];
        }
        __syncthreads();

        if (tid < 64) {
            float dsum = 0.f;
#pragma unroll 8
            for (int kk = 0; kk < 64; ++kk) dsum += qsT[kk][tid] * ksum_l[kk];
            denom_l[tid] = nn + inv * dsum;
        }
        __syncthreads();

        float dot[4][4] = {};
#pragma unroll 8
        for (int kk = 0; kk < 64; ++kk) {
            float4 av  = *(const float4*)&qsT[kk][ty << 2];
            float4 bv4 = *(const float4*)&kvs[kk * 64 + (tx << 2)];
            float a[4] = {av.x, av.y, av.z, av.w};
            float bvals[4] = {bv4.x, bv4.y, bv4.z, bv4.w};
#pragma unroll
            for (int i = 0; i < 4; ++i)
#pragma unroll
                for (int j = 0; j < 4; ++j)
                    dot[i][j] = fmaf(a[i], bvals[j], dot[i][j]);
        }
        float rden[4];
#pragma unroll
        for (int i = 0; i < 4; ++i) rden[i] = 0.25f / denom_l[(ty << 2) + i];
#pragma unroll
        for (int i = 0; i < 4; ++i)
#pragma unroll
            for (int j = 0; j < 4; ++j)
                acc[i][j] += (inv * dot[i][j] + vsum_l[(tx << 2) + j]) * rden[i];
    }

#pragma unroll
    for (int i = 0; i < 4; ++i) {
        const size_t node = (size_t)b * MM + m0 + (ty << 2) + i;
        *(float4*)&out[node * DD + (tx << 2)] =
            make_float4(acc[i][0], acc[i][1], acc[i][2], acc[i][3]);
    }
}

// ---------------------------------------------------------------------------
// GCN gather: one wave per destination node; lane = feature. No atomics.
// ---------------------------------------------------------------------------
__global__ __launch_bounds__(256) void gcn_gather(
    const int* __restrict__ offsets, const int* __restrict__ rowbuf,
    const float* __restrict__ valbuf, const float* __restrict__ vbar,
    float* __restrict__ out)
{
    const int t = blockIdx.x * 256 + threadIdx.x;
    const int n = t >> 6, d = t & 63;
    const int s = offsets[n], e = offsets[n + 1];
    float acc = 0.f;
    int i = s;
    for (; i + 4 <= e; i += 4) {
        const int r0 = rowbuf[i], r1 = rowbuf[i + 1], r2 = rowbuf[i + 2], r3 = rowbuf[i + 3];
        const float w0 = valbuf[i], w1 = valbuf[i + 1], w2 = valbuf[i + 2], w3 = valbuf[i + 3];
        acc += w0 * vbar[(size_t)r0 * DD + d];
        acc += w1 * vbar[(size_t)r1 * DD + d];
        acc += w2 * vbar[(size_t)r2 * DD + d];
        acc += w3 * vbar[(size_t)r3 * DD + d];
    }
    for (; i < e; ++i)
        acc += valbuf[i] * vbar[(size_t)rowbuf[i] * DD + d];
    out[(size_t)n * DD + d] += acc;
}

// ---------------------------------------------------------------------------
extern "C" void kernel_launch(void* const* d_in, const int* in_sizes, int n_in,
                              void* d_out, int out_size, void* d_ws, size_t ws_size,
                              hipStream_t stream)
{
    (void)in_sizes; (void)n_in; (void)out_size; (void)ws_size;
    const float* Xq = (const float*)d_in[0];
    const float* Xs = (const float*)d_in[1];
    const float* ew = (const float*)d_in[2];
    const float* Wq = (const float*)d_in[3];
    const float* bq = (const float*)d_in[4];
    const float* Wk = (const float*)d_in[5];
    const float* bk = (const float*)d_in[6];
    const float* Wv = (const float*)d_in[7];
    const float* bv = (const float*)d_in[8];
    const int* n_nodes = (const int*)d_in[9];
    const int* ei = (const int*)d_in[10];
    float* out = (float*)d_out;
    float* ws  = (float*)d_ws;

    // workspace layout (float units); q/k/v are bf16 (half-float footprint)
    const size_t SZ_QKV  = (size_t)NN * HD / 2;        // 4194304 floats each
    const size_t OFF_Q    = 0;
    const size_t OFF_K    = SZ_QKV;
    const size_t OFF_V    = SZ_QKV * 2;
    const size_t OFF_SS   = SZ_QKV * 3;                // 16 floats
    const size_t OFF_DEG  = OFF_SS + 16;               // NN ints (zeroed)
    const size_t OFF_CUR  = OFF_DEG + NN;              // NN ints (zeroed)
    const size_t OFF_KV   = OFF_CUR + NN;              // BB*HH*4*4096 parts
    const size_t OFF_KSUM = OFF_KV + (size_t)BB * HH * 4 * 4096;
    const size_t OFF_VSUM = OFF_KSUM + (size_t)BB * HH * 4 * 64;
    const size_t OFF_OFFS = OFF_VSUM + (size_t)BB * HH * 4 * 64;  // NN+1
    const size_t OFF_ROWB = OFF_OFFS + NN + 16;        // EE ints
    const size_t OFF_VALB = OFF_ROWB + EE;             // EE floats
    const size_t OFF_VBAR = OFF_VALB + EE;             // NN*DD
    // total ≈ 81 MB

    ushort* q16   = (ushort*)(ws + OFF_Q);
    ushort* k16   = (ushort*)(ws + OFF_K);
    ushort* v16   = (ushort*)(ws + OFF_V);
    float* sumsq  = ws + OFF_SS;
    ushort* WT    = (ushort*)(ws + OFF_DEG);  // aliases deg/cursor: dead after gemm
    int*   deg    = (int*)(ws + OFF_DEG);
    int*   cursor = (int*)(ws + OFF_CUR);
    float* kv_p   = ws + OFF_KV;
    float* ksum_p = ws + OFF_KSUM;
    float* vsum_p = ws + OFF_VSUM;
    int*   offs   = (int*)(ws + OFF_OFFS);
    int*   rowbuf = (int*)(ws + OFF_ROWB);
    float* valbuf = ws + OFF_VALB;
    float* vbar   = ws + OFF_VBAR;

    hipMemsetAsync(sumsq, 0, 16 * sizeof(float), stream);
    convert_w<<<768, 256, 0, stream>>>(Wq, Wk, Wv, WT);
    qkv_gemm<<<1536, 256, 0, stream>>>(
        Xq, Xs, WT, bq, bk, bv, q16, k16, v16, sumsq);
    // WT dead; zero deg + cursor
    hipMemsetAsync(ws + OFF_DEG, 0, 2 * NN * sizeof(int), stream);
    deg_kernel<<<EE / 256, 256, 0, stream>>>(ei, deg);
    scan_kernel<<<1, 1024, 0, stream>>>(deg, offs);
    bucket_kernel<<<EE / 256, 256, 0, stream>>>(ei, ew, deg, offs, cursor, rowbuf, valbuf);
    kv_mfma<<<dim3(HH, BB, 4), 256, 0, stream>>>(k16, v16, kv_p, ksum_p, vsum_p);
    vbar_kernel<<<(NN * DD) / 256, 256, 0, stream>>>(v16, vbar);
    attn_kernel<<<dim3(MM / 64, BB), 256, 0, stream>>>(
        q16, kv_p, ksum_p, vsum_p, sumsq, n_nodes, out);
    gcn_gather<<<(NN * DD) / 256, 256, 0, stream>>>(offs, rowbuf, valbuf, vbar, out);
}